// Round 4
// baseline (5740.243 us; speedup 1.0000x reference)
//
#include <hip/hip_runtime.h>
#include <hip/hip_bf16.h>
#include <math.h>

// ---------------------------------------------------------------------------
// Sizes
//   x: (256,1,22,1000)  conv1 (22,1,22,1) VALID -> (256,22,1,1000)
//   conv2 (25,22,1,12) pad (6,6) -> (256,25,1,1001); sig=(256,25,1001)
//   epochs lens = [334,334,333]; covs: (256,3,25,25); windows m=30
// ---------------------------------------------------------------------------

// ---------------- conv1 + bn1 ----------------
__global__ __launch_bounds__(256) void conv1_kernel(
    const float* __restrict__ x, const float* __restrict__ c1w, const float* __restrict__ c1b,
    const float* __restrict__ g, const float* __restrict__ be, const float* __restrict__ mu,
    const float* __restrict__ va, float* __restrict__ ybn1)
{
  __shared__ float w[484];
  __shared__ float scl[22], sft[22];
  int t = threadIdx.x;
  for (int e = t; e < 484; e += 256) w[e] = c1w[e];
  if (t < 22) { float inv = g[t] / sqrtf(va[t] + 1e-5f); scl[t] = inv; sft[t] = be[t] - mu[t]*inv; }
  __syncthreads();
  int gid = blockIdx.x*256 + t;
  int b = gid / 1000, wp = gid % 1000;
  const float* xb = x + (size_t)b*22000 + wp;
  float acc[22];
  #pragma unroll
  for (int o = 0; o < 22; ++o) acc[o] = c1b[o];
  for (int h = 0; h < 22; ++h) {
    float xv = xb[h*1000];
    #pragma unroll
    for (int o = 0; o < 22; ++o) acc[o] += xv * w[o*22 + h];
  }
  float* yb = ybn1 + (size_t)b*22000 + wp;
  #pragma unroll
  for (int o = 0; o < 22; ++o) yb[o*1000] = acc[o]*scl[o] + sft[o];
}

// ---------------- conv2 + bn2 ----------------
__global__ __launch_bounds__(256) void conv2_kernel(
    const float* __restrict__ ybn1, const float* __restrict__ c2w, const float* __restrict__ c2b,
    const float* __restrict__ g, const float* __restrict__ be, const float* __restrict__ mu,
    const float* __restrict__ va, float* __restrict__ sig)
{
  __shared__ float w[6600];
  __shared__ float scl[25], sft[25];
  int t = threadIdx.x;
  for (int e = t; e < 6600; e += 256) w[e] = c2w[e];
  if (t < 25) { float inv = g[t] / sqrtf(va[t] + 1e-5f); scl[t] = inv; sft[t] = be[t] - mu[t]*inv; }
  __syncthreads();
  int gid = blockIdx.x*256 + t;
  if (gid >= 256*1001) return;
  int b = gid / 1001, wp = gid % 1001;
  const float* yb = ybn1 + (size_t)b*22000;
  float acc[25];
  #pragma unroll
  for (int p = 0; p < 25; ++p) acc[p] = c2b[p];
  for (int c = 0; c < 22; ++c) {
    for (int kw = 0; kw < 12; ++kw) {
      int wi = wp - 6 + kw;
      if (wi < 0 || wi >= 1000) continue;
      float v = yb[c*1000 + wi];
      #pragma unroll
      for (int p = 0; p < 25; ++p) acc[p] += v * w[p*264 + c*12 + kw];
    }
  }
  float* sb = sig + (size_t)b*25025 + wp;
  #pragma unroll
  for (int p = 0; p < 25; ++p) sb[p*1001] = acc[p]*scl[p] + sft[p];
}

// ---------------- signal2spd ----------------
__global__ __launch_bounds__(256) void spd_kernel(const float* __restrict__ sig, float* __restrict__ covs)
{
  __shared__ float s[25*334];
  __shared__ float mean[25];
  __shared__ float cv[625];
  __shared__ float tra;
  int bt = blockIdx.x; int b = bt/3, ep = bt%3;
  int off = ep*334;
  int Lp = (ep < 2) ? 334 : 333;
  int t = threadIdx.x;
  const float* sb = sig + (size_t)b*25025;
  for (int e = t; e < 25*Lp; e += 256) { int c = e / Lp, tt = e % Lp; s[c*334 + tt] = sb[c*1001 + off + tt]; }
  __syncthreads();
  if (t < 25) { float m = 0.f; for (int i = 0; i < Lp; ++i) m += s[t*334 + i]; mean[t] = m / (float)Lp; }
  __syncthreads();
  for (int pi = t; pi < 325; pi += 256) {
    int i = 0, rem = pi;
    while (rem >= 25 - i) { rem -= 25 - i; ++i; }
    int j = i + rem;
    float mi = mean[i], mj = mean[j], acc = 0.f;
    for (int k = 0; k < Lp; ++k) acc += (s[i*334 + k] - mi) * (s[j*334 + k] - mj);
    float v = acc / (float)(Lp - 1);
    cv[i*25 + j] = v; cv[j*25 + i] = v;
  }
  __syncthreads();
  if (t == 0) { float tr = 0.f; for (int i = 0; i < 25; ++i) tr += cv[i*26]; tra = tr; }
  __syncthreads();
  float inv = 1.f / tra;
  for (int e = t; e < 625; e += 256) {
    int i = e / 25, j = e % 25;
    covs[(size_t)bt*625 + e] = cv[e]*inv + ((i == j) ? 1e-5f : 0.f);
  }
}

// ---------------- build V / K / Q29 ----------------
__global__ __launch_bounds__(64) void build_windows_kernel(
    const float* __restrict__ covs,
    const float* __restrict__ sk0, const float* __restrict__ sk1, const float* __restrict__ sk2, const float* __restrict__ sk3,
    const float* __restrict__ sv0, const float* __restrict__ sv1, const float* __restrict__ sv2, const float* __restrict__ sv3,
    const float* __restrict__ sq3,
    float* __restrict__ Vbuf, float* __restrict__ Kbuf, float* __restrict__ Qbuf)
{
  __shared__ float sSub[625], sSv[625], sTmp[625], sSk[100], sTk[100];
  int bw = blockIdx.x;
  int bt = bw / 30, win = bw % 30;
  int t = threadIdx.x;
  int k, r0, c0;
  const float* sv; const float* sk;
  if (win < 16)      { k = 2; r0 = win/4;        c0 = win%4;        sv = sv0; sk = sk0; }
  else if (win < 25) { k = 3; int u = win-16; r0 = u/3; c0 = u%3;   sv = sv1; sk = sk1; }
  else if (win < 29) { k = 4; int u = win-25; r0 = u/2; c0 = u%2;   sv = sv2; sk = sk2; }
  else               { k = 5; r0 = 0;            c0 = 0;            sv = sv3; sk = sk3; }
  int kk = k*k;
  const float* cov = covs + (size_t)bt*625;
  for (int e = t; e < kk*kk; e += 64) {
    int p = e / kk, q = e % kk;
    int ip = (r0 + p/k)*5 + (c0 + p%k);
    int iq = (r0 + q/k)*5 + (c0 + q%k);
    sSub[p*kk + q] = cov[ip*25 + iq];
  }
  for (int e = t; e < kk*25; e += 64) sSv[e] = sv[e];
  for (int e = t; e < kk*4; e += 64)  sSk[e] = sk[e];
  __syncthreads();
  for (int e = t; e < kk*25; e += 64) {
    int i = e / 25, b = e % 25;
    float acc = 0.f;
    for (int j = 0; j < kk; ++j) acc += sSub[i*kk + j] * sSv[j*25 + b];
    sTmp[e] = acc;
  }
  for (int e = t; e < kk*4; e += 64) {
    int i = e / 4, b = e % 4;
    float acc = 0.f;
    for (int j = 0; j < kk; ++j) acc += sSub[i*kk + j] * sSk[j*4 + b];
    sTk[e] = acc;
  }
  __syncthreads();
  float* Vout = Vbuf + (size_t)bw*625;
  for (int e = t; e < 625; e += 64) {
    int a = e / 25, b = e % 25;
    float acc = 0.f;
    for (int i = 0; i < kk; ++i) acc += sSv[i*25 + a] * sTmp[i*25 + b];
    if (a == b) acc += 4e-6f * (float)(1 + a);
    Vout[e] = acc;
  }
  float* Kout = Kbuf + (size_t)bw*16;
  for (int e = t; e < 16; e += 64) {
    int a = e / 4, b = e % 4;
    float acc = 0.f;
    for (int i = 0; i < kk; ++i) acc += sSk[i*4 + a] * sTk[i*4 + b];
    if (a == b) acc += 2.5e-5f * (float)(1 + a);
    Kout[e] = acc;
  }
  if (win == 29) {
    __syncthreads();
    for (int e = t; e < 100; e += 64) {
      int i = e / 4, b = e % 4;
      float acc = 0.f;
      for (int j = 0; j < 25; ++j) acc += sSub[i*25 + j] * sq3[j*4 + b];
      sTk[e] = acc;
    }
    __syncthreads();
    float* Qout = Qbuf + (size_t)bt*16;
    for (int e = t; e < 16; e += 64) {
      int a = e / 4, b = e % 4;
      float acc = 0.f;
      for (int i = 0; i < 25; ++i) acc += sq3[i*4 + a] * sTk[i*4 + b];
      if (a == b) acc += 2.5e-5f * (float)(1 + a);
      Qout[e] = acc;
    }
  }
}

// ---------------- batched eigh via ONE-SIDED (Hestenes) Jacobi ----------------
// G = A (+SHIFT*I); right rotations orthogonalize columns. lambda_i = ||g_i||,
// u_i = g_i/lambda_i. No eigenvector matrix, fused single-phase rounds,
// relative convergence criterion. MODE 0: f=log(max(w,1e-9));
// MODE 1: f=max(exp(w),1e-4); MODE 2: f=max(w, ln 1e-4). w = lambda - SHIFT.
template<int NDATA, int MODE, int SHIFT>
__global__ __launch_bounds__(64) void eigh1s_kernel(float* __restrict__ mats, float* __restrict__ norms_out)
{
  constexpr int NPAD = (NDATA + 1) & ~1;   // 26 / 18
  constexpr int NR = NPAD - 1;             // rounds per sweep
  constexpr int NP = NPAD / 2;             // disjoint pairs per round
  constexpr int LDC = NPAD + 1;            // odd leading dim (banks)
  constexpr int NCH = (NP + 1) / 2;        // 2 pairs (32 lanes each) per chunk
  constexpr int NT = NDATA*(NDATA+1)/2;

  __shared__ float G[NDATA*LDC];
  __shared__ float Gs[NDATA*LDC];
  __shared__ float nrm[NPAD];
  __shared__ float wv[NPAD];
  __shared__ unsigned pqt[NR*NP];

  int t = threadIdx.x;
  float* M = mats + (size_t)blockIdx.x*(NDATA*NDATA);

  // --- pair-schedule table (round-robin tournament), packed p|q<<8 ---
  for (int e = t; e < NR*NP; e += 64) {
    int r = e / NP, i = e - r*NP;
    int p, q;
    if (i == 0) { p = NPAD-1; q = r; }
    else {
      p = r + i; if (p >= NR) p -= NR;
      q = r - i; if (q < 0)   q += NR;
    }
    pqt[e] = (unsigned)p | ((unsigned)q << 8);
  }
  // --- load G = sym(M) (+shift), zero pad column ---
  for (int e = t; e < NDATA*LDC; e += 64) {
    int i = e / LDC, j = e - i*LDC;
    float v = 0.f;
    if (j < NDATA) {
      v = 0.5f*(M[i*NDATA + j] + M[j*NDATA + i]);
      if (i == j) v += (float)SHIFT;
    }
    G[e] = v;
  }
  __syncthreads();
  // --- initial column norms ---
  if (t < NPAD) {
    float s = 0.f;
    for (int r = 0; r < NDATA; ++r) { float g = G[r*LDC + t]; s += g*g; }
    nrm[t] = s;
  }
  __syncthreads();

  int g32 = t >> 5;
  int kx  = t & 31;
  bool rv = kx < NDATA;
  int kbase = (rv ? kx : 0) * LDC;

  for (int sw = 0; sw < 12; ++sw) {
    float relmax = 0.f;
    for (int r = 0; r < NR; ++r) {
      #pragma unroll
      for (int m = 0; m < NCH; ++m) {
        int pi = 2*m + g32;
        bool pv = pi < NP;
        unsigned pq = pqt[r*NP + (pv ? pi : NP-1)];
        int p = (int)(pq & 255u), q = (int)((pq >> 8) & 255u);
        int ap = kbase + p, aq = kbase + q;
        float x = G[ap], y = G[aq];
        float prod = rv ? x*y : 0.f;
        prod += __shfl_xor(prod, 1);
        prod += __shfl_xor(prod, 2);
        prod += __shfl_xor(prod, 4);
        prod += __shfl_xor(prod, 8);
        prod += __shfl_xor(prod, 16);
        float d = prod;
        float np_ = nrm[p], nq_ = nrm[q];
        // rotation (robust, branchless): tau = (nq-np)/(2d)
        float ad = fabsf(d);
        float dd = (ad > 1e-36f) ? d : 1e-36f;
        float tau = (nq_ - np_) * 0.5f * __builtin_amdgcn_rcpf(dd);
        float mag = __builtin_amdgcn_rcpf(fabsf(tau) + sqrtf(tau*tau + 1.f));
        float tt = copysignf(mag, tau);
        float c = __builtin_amdgcn_rsqf(tt*tt + 1.f);
        float s = tt * c;
        float gp = c*x - s*y;
        float gq = s*x + c*y;
        if (rv && pv) { G[ap] = gp; G[aq] = gq; }
        float c2 = c*c, s2 = s*s, csd = 2.f*c*s*d;
        if (kx == 0 && pv) {
          nrm[p] = c2*np_ - csd + s2*nq_;
          nrm[q] = s2*np_ + csd + c2*nq_;
        }
        relmax = fmaxf(relmax, d*d * __builtin_amdgcn_rcpf(fmaxf(np_*nq_, 1e-30f)));
      }
      __syncthreads();
    }
    // exact norm refresh (kills incremental drift; needed for w anyway)
    if (t < NPAD) {
      float s = 0.f;
      for (int r = 0; r < NDATA; ++r) { float g = G[r*LDC + t]; s += g*g; }
      nrm[t] = s;
    }
    __syncthreads();
    if (sw >= 1) {
      #pragma unroll
      for (int o = 32; o > 0; o >>= 1) relmax = fmaxf(relmax, __shfl_xor(relmax, o));
      if (relmax < 9e-10f) break;   // (3e-5)^2 relative
    }
  }

  // --- weights w_i = f(lambda_i - SHIFT) / lambda_i^2 ---
  if (t < NPAD) {
    float n2 = nrm[t];
    float lam = sqrtf(n2) - (float)SHIFT;
    float f;
    if (MODE == 0)      f = logf(fmaxf(lam, 1e-9f));
    else if (MODE == 1) f = fmaxf(expf(lam), 1e-4f);
    else                f = fmaxf(lam, -9.210340371976182f);
    wv[t] = (n2 < 1e-30f) ? 0.f : f * __builtin_amdgcn_rcpf(n2);
  }
  __syncthreads();
  // --- Gs = G * diag(w) ---
  for (int e = t; e < NDATA*LDC; e += 64) {
    int j = e % LDC;
    Gs[e] = G[e] * ((j < NPAD) ? wv[j] : 0.f);
  }
  __syncthreads();
  // --- M = Gs * G^T (triangle, mirrored) + optional Frobenius^2 ---
  float nacc = 0.f;
  for (int e = t; e < NT; e += 64) {
    int i = 0, rem = e;
    while (rem >= NDATA - i) { rem -= NDATA - i; ++i; }
    int j = i + rem;
    int bi = i*LDC, bj = j*LDC;
    float acc = 0.f;
    #pragma unroll
    for (int k = 0; k < NPAD; ++k) acc += Gs[bi + k] * G[bj + k];
    M[i*NDATA + j] = acc;
    M[j*NDATA + i] = acc;
    nacc += (i == j) ? acc*acc : 2.f*acc*acc;
  }
  if (norms_out != nullptr) {
    #pragma unroll
    for (int o = 32; o > 0; o >>= 1) nacc += __shfl_down(nacc, o);
    if (t == 0) norms_out[blockIdx.x] = nacc;
  }
}

// ---------------- per-thread 4x4 eigh -> log + Frobenius^2 ----------------
template<int P, int Q>
__device__ __forceinline__ void rot4(float a[4][4], float u[4][4])
{
  float apq = a[P][Q];
  if (fabsf(apq) < 1e-36f) return;
  float app = a[P][P], aqq = a[Q][Q];
  float tau = (aqq - app) / (2.f*apq);
  float tt = 1.f / (fabsf(tau) + sqrtf(tau*tau + 1.f));
  if (tau < 0.f) tt = -tt;
  float c = 1.f / sqrtf(tt*tt + 1.f), s = tt*c;
  #pragma unroll
  for (int k = 0; k < 4; ++k) { float akp = a[k][P], akq = a[k][Q]; a[k][P] = c*akp - s*akq; a[k][Q] = s*akp + c*akq; }
  #pragma unroll
  for (int k = 0; k < 4; ++k) { float apk = a[P][k], aqk = a[Q][k]; a[P][k] = c*apk - s*aqk; a[Q][k] = s*apk + c*aqk; }
  #pragma unroll
  for (int k = 0; k < 4; ++k) { float ukp = u[k][P], ukq = u[k][Q]; u[k][P] = c*ukp - s*ukq; u[k][Q] = s*ukp + c*ukq; }
}

__global__ __launch_bounds__(256) void eigh4_kernel(float* __restrict__ kmats, float* __restrict__ qmats,
                                                    float* __restrict__ norms)
{
  int idx = blockIdx.x*256 + threadIdx.x;
  if (idx >= 23808) return;
  float* M = (idx < 23040) ? (kmats + (size_t)idx*16) : (qmats + (size_t)(idx - 23040)*16);
  float a[4][4], u[4][4];
  #pragma unroll
  for (int i = 0; i < 4; ++i)
    #pragma unroll
    for (int j = 0; j < 4; ++j) { a[i][j] = 0.5f*(M[i*4+j] + M[j*4+i]); u[i][j] = (i == j) ? 1.f : 0.f; }
  #pragma unroll 1
  for (int sw = 0; sw < 8; ++sw) {
    rot4<0,1>(a,u); rot4<0,2>(a,u); rot4<0,3>(a,u);
    rot4<1,2>(a,u); rot4<1,3>(a,u); rot4<2,3>(a,u);
  }
  float f[4];
  #pragma unroll
  for (int i = 0; i < 4; ++i) f[i] = logf(fmaxf(a[i][i], 1e-9f));
  float nrm = 0.f;
  #pragma unroll
  for (int i = 0; i < 4; ++i)
    #pragma unroll
    for (int j = 0; j < 4; ++j) {
      float acc = 0.f;
      #pragma unroll
      for (int k = 0; k < 4; ++k) acc += u[i][k]*f[k]*u[j][k];
      M[i*4+j] = acc; nrm += acc*acc;
    }
  norms[idx] = nrm;
}

// ---------------- attention 1 (only output row 29) ----------------
__global__ __launch_bounds__(64) void att1_kernel(
    const float* __restrict__ logK, const float* __restrict__ logQ,
    const float* __restrict__ kn, const float* __restrict__ qn,
    const float* __restrict__ logV, float* __restrict__ outlog1)
{
  __shared__ float lq[16];
  __shared__ float sscore[30];
  __shared__ float sp[30];
  int bt = blockIdx.x, t = threadIdx.x;
  if (t < 16) lq[t] = logQ[(size_t)bt*16 + t];
  __syncthreads();
  if (t < 30) {
    const float* lk = logK + ((size_t)bt*30 + t)*16;
    float cr = 0.f;
    #pragma unroll
    for (int e = 0; e < 16; ++e) cr += lk[e]*lq[e];
    float E = fmaxf(kn[bt*30 + t] + qn[bt] - 2.f*cr, 0.f);
    sscore[t] = 1.f/(1.f + log1pf(E));
  }
  __syncthreads();
  float mx = -1e30f;
  for (int i = 0; i < 30; ++i) mx = fmaxf(mx, sscore[i]);
  float sm = 0.f;
  for (int i = 0; i < 30; ++i) sm += expf(sscore[i] - mx);
  if (t < 30) sp[t] = expf(sscore[t] - mx)/sm;
  __syncthreads();
  const float* lv = logV + (size_t)bt*30*625;
  float* outp = outlog1 + (size_t)bt*625;
  for (int e = t; e < 625; e += 64) {
    float acc = 0.f;
    for (int i = 0; i < 30; ++i) acc += sp[i]*lv[(size_t)i*625 + e];
    outp[e] = acc;
  }
}

// ---------------- Q2/K2/V2 = W^T xm W ----------------
__global__ __launch_bounds__(64) void qkv2_kernel(
    const float* __restrict__ xm, const float* __restrict__ mq, const float* __restrict__ mk,
    const float* __restrict__ mv, float* __restrict__ q2, float* __restrict__ k2, float* __restrict__ v2)
{
  __shared__ float sx[625], sw[450], stmp[450];
  int bt = blockIdx.x, t = threadIdx.x;
  for (int e = t; e < 625; e += 64) sx[e] = xm[(size_t)bt*625 + e];
  for (int wi = 0; wi < 3; ++wi) {
    const float* W = (wi == 0) ? mq : (wi == 1) ? mk : mv;
    float* O = ((wi == 0) ? q2 : (wi == 1) ? k2 : v2) + (size_t)bt*324;
    for (int e = t; e < 450; e += 64) sw[e] = W[e];
    __syncthreads();
    for (int e = t; e < 450; e += 64) {
      int i = e / 18, b = e % 18;
      float acc = 0.f;
      for (int j = 0; j < 25; ++j) acc += sx[i*25 + j]*sw[j*18 + b];
      stmp[e] = acc;
    }
    __syncthreads();
    for (int e = t; e < 324; e += 64) {
      int a = e / 18, b = e % 18;
      float acc = 0.f;
      for (int i = 0; i < 25; ++i) acc += sw[i*18 + a]*stmp[i*18 + b];
      O[e] = acc;
    }
    __syncthreads();
  }
}

// ---------------- attention 2 ----------------
__global__ __launch_bounds__(64) void att2_kernel(
    const float* __restrict__ logQ2, const float* __restrict__ logK2, const float* __restrict__ logV2,
    const float* __restrict__ norms, float* __restrict__ outlog2)
{
  __shared__ float S[3][3];
  __shared__ float PT[3][3];
  int b = blockIdx.x, t = threadIdx.x;
  if (t < 9) {
    int i = t / 3, j = t % 3;
    const float* lk = logK2 + ((size_t)b*3 + i)*324;
    const float* lq = logQ2 + ((size_t)b*3 + j)*324;
    float cr = 0.f;
    for (int e = 0; e < 324; ++e) cr += lk[e]*lq[e];
    float E = fmaxf(norms[768 + b*3 + i] + norms[b*3 + j] - 2.f*cr, 0.f);
    S[i][j] = 1.f/(1.f + log1pf(E));
  }
  __syncthreads();
  if (t < 3) {
    float m = fmaxf(S[0][t], fmaxf(S[1][t], S[2][t]));
    float e0 = expf(S[0][t]-m), e1 = expf(S[1][t]-m), e2 = expf(S[2][t]-m);
    float ssum = e0 + e1 + e2;
    PT[t][0] = e0/ssum; PT[t][1] = e1/ssum; PT[t][2] = e2/ssum;
  }
  __syncthreads();
  for (int e = t; e < 324; e += 64) {
    float l0 = logV2[((size_t)b*3 + 0)*324 + e];
    float l1 = logV2[((size_t)b*3 + 1)*324 + e];
    float l2 = logV2[((size_t)b*3 + 2)*324 + e];
    #pragma unroll
    for (int j = 0; j < 3; ++j)
      outlog2[((size_t)b*3 + j)*324 + e] = PT[j][0]*l0 + PT[j][1]*l1 + PT[j][2]*l2;
  }
}

// ---------------- features + linear ----------------
__global__ __launch_bounds__(64) void feat_kernel(
    const float* __restrict__ Lg, const float* __restrict__ lw, const float* __restrict__ lb,
    float* __restrict__ outp)
{
  __shared__ int tri_i[171], tri_j[171];
  int b = blockIdx.x, t = threadIdx.x;
  if (t == 0) { int f = 0; for (int i = 0; i < 18; ++i) for (int j = i; j < 18; ++j) { tri_i[f] = i; tri_j[f] = j; ++f; } }
  __syncthreads();
  float a0 = 0.f, a1 = 0.f, a2 = 0.f, a3 = 0.f;
  const float SQ2 = 1.41421356237309515f;
  for (int f = t; f < 513; f += 64) {
    int tt = f / 171, r = f % 171;
    int i = tri_i[r], j = tri_j[r];
    float coef = (i == j) ? 1.f : SQ2;
    float v = Lg[((size_t)b*3 + tt)*324 + i*18 + j] * coef;
    a0 += v*lw[0*513 + f]; a1 += v*lw[1*513 + f]; a2 += v*lw[2*513 + f]; a3 += v*lw[3*513 + f];
  }
  #pragma unroll
  for (int off = 32; off > 0; off >>= 1) {
    a0 += __shfl_down(a0, off); a1 += __shfl_down(a1, off);
    a2 += __shfl_down(a2, off); a3 += __shfl_down(a3, off);
  }
  if (t == 0) {
    outp[b*4 + 0] = a0 + lb[0]; outp[b*4 + 1] = a1 + lb[1];
    outp[b*4 + 2] = a2 + lb[2]; outp[b*4 + 3] = a3 + lb[3];
  }
}

// ---------------------------------------------------------------------------
extern "C" void kernel_launch(void* const* d_in, const int* in_sizes, int n_in,
                              void* d_out, int out_size, void* d_ws, size_t ws_size,
                              hipStream_t stream)
{
  const float* x    = (const float*)d_in[0];
  const float* c1w  = (const float*)d_in[1];
  const float* c1b  = (const float*)d_in[2];
  const float* bn1g = (const float*)d_in[3];
  const float* bn1b = (const float*)d_in[4];
  const float* bn1m = (const float*)d_in[5];
  const float* bn1v = (const float*)d_in[6];
  const float* c2w  = (const float*)d_in[7];
  const float* c2b  = (const float*)d_in[8];
  const float* bn2g = (const float*)d_in[9];
  const float* bn2b = (const float*)d_in[10];
  const float* bn2m = (const float*)d_in[11];
  const float* bn2v = (const float*)d_in[12];
  const float* sk0  = (const float*)d_in[14];
  const float* sv0  = (const float*)d_in[15];
  const float* sk1  = (const float*)d_in[17];
  const float* sv1  = (const float*)d_in[18];
  const float* sk2  = (const float*)d_in[20];
  const float* sv2  = (const float*)d_in[21];
  const float* sq3  = (const float*)d_in[22];
  const float* sk3  = (const float*)d_in[23];
  const float* sv3  = (const float*)d_in[24];
  const float* mq   = (const float*)d_in[25];
  const float* mk   = (const float*)d_in[26];
  const float* mv   = (const float*)d_in[27];
  const float* lw   = (const float*)d_in[28];
  const float* lb   = (const float*)d_in[29];
  float* outp = (float*)d_out;

  float* ws = (float*)d_ws;
  float* covs = ws;                       // 480000
  float* ybn1 = ws + 480000;              // 5632000
  float* sig  = ws + 6112000;             // 6406400
  float* Vbuf = ws + 480000;              // 14400000 (reuses dead ybn1/sig)
  float* Kbuf = ws + 14880000;            // 368640
  float* Qbuf = ws + 15248640;            // 12288
  float* knb  = ws + 15260928;            // 23808
  float* ol1  = ws + 15284736;            // 480000
  float* qkv2 = ws + 15764736;            // 746496
  float* nrm2 = ws + 16511232;            // 2304
  float* ol2  = ws + 16513536;            // 248832

  conv1_kernel<<<1000, 256, 0, stream>>>(x, c1w, c1b, bn1g, bn1b, bn1m, bn1v, ybn1);
  conv2_kernel<<<1001, 256, 0, stream>>>(ybn1, c2w, c2b, bn2g, bn2b, bn2m, bn2v, sig);
  spd_kernel<<<768, 256, 0, stream>>>(sig, covs);
  build_windows_kernel<<<23040, 64, 0, stream>>>(covs, sk0, sk1, sk2, sk3, sv0, sv1, sv2, sv3, sq3,
                                                 Vbuf, Kbuf, Qbuf);
  eigh1s_kernel<25,0,0><<<23040, 64, 0, stream>>>(Vbuf, nullptr);          // logV in place
  eigh4_kernel<<<93, 256, 0, stream>>>(Kbuf, Qbuf, knb);                   // logK/logQ + norms
  att1_kernel<<<768, 64, 0, stream>>>(Kbuf, Qbuf, knb, knb + 23040, Vbuf, ol1);
  eigh1s_kernel<25,1,16><<<768, 64, 0, stream>>>(ol1, nullptr);            // xm = rect(exp(.)), shifted
  qkv2_kernel<<<768, 64, 0, stream>>>(ol1, mq, mk, mv, qkv2, qkv2 + 248832, qkv2 + 497664);
  eigh1s_kernel<18,0,0><<<2304, 64, 0, stream>>>(qkv2, nrm2);              // logs + norms
  att2_kernel<<<256, 64, 0, stream>>>(qkv2, qkv2 + 248832, qkv2 + 497664, nrm2, ol2);
  eigh1s_kernel<18,2,16><<<768, 64, 0, stream>>>(ol2, nullptr);            // Lg, shifted
  feat_kernel<<<256, 64, 0, stream>>>(ol2, lw, lb, outp);
}

// Round 5
// 1430.128 us; speedup vs baseline: 4.0138x; 4.0138x over previous
//
#include <hip/hip_runtime.h>
#include <hip/hip_bf16.h>
#include <math.h>

// ---------------------------------------------------------------------------
// Sizes
//   x: (256,1,22,1000)  conv1 (22,1,22,1) VALID -> (256,22,1,1000)
//   conv2 (25,22,1,12) pad (6,6) -> (256,25,1,1001); sig=(256,25,1001)
//   epochs lens = [334,334,333]; covs: (256,3,25,25); windows m=30
// ---------------------------------------------------------------------------

// ---------------- conv1 + bn1 ----------------
__global__ __launch_bounds__(256) void conv1_kernel(
    const float* __restrict__ x, const float* __restrict__ c1w, const float* __restrict__ c1b,
    const float* __restrict__ g, const float* __restrict__ be, const float* __restrict__ mu,
    const float* __restrict__ va, float* __restrict__ ybn1)
{
  __shared__ float w[484];
  __shared__ float scl[22], sft[22];
  int t = threadIdx.x;
  for (int e = t; e < 484; e += 256) w[e] = c1w[e];
  if (t < 22) { float inv = g[t] / sqrtf(va[t] + 1e-5f); scl[t] = inv; sft[t] = be[t] - mu[t]*inv; }
  __syncthreads();
  int gid = blockIdx.x*256 + t;
  int b = gid / 1000, wp = gid % 1000;
  const float* xb = x + (size_t)b*22000 + wp;
  float acc[22];
  #pragma unroll
  for (int o = 0; o < 22; ++o) acc[o] = c1b[o];
  for (int h = 0; h < 22; ++h) {
    float xv = xb[h*1000];
    #pragma unroll
    for (int o = 0; o < 22; ++o) acc[o] += xv * w[o*22 + h];
  }
  float* yb = ybn1 + (size_t)b*22000 + wp;
  #pragma unroll
  for (int o = 0; o < 22; ++o) yb[o*1000] = acc[o]*scl[o] + sft[o];
}

// ---------------- conv2 + bn2 ----------------
__global__ __launch_bounds__(256) void conv2_kernel(
    const float* __restrict__ ybn1, const float* __restrict__ c2w, const float* __restrict__ c2b,
    const float* __restrict__ g, const float* __restrict__ be, const float* __restrict__ mu,
    const float* __restrict__ va, float* __restrict__ sig)
{
  __shared__ float w[6600];
  __shared__ float scl[25], sft[25];
  int t = threadIdx.x;
  for (int e = t; e < 6600; e += 256) w[e] = c2w[e];
  if (t < 25) { float inv = g[t] / sqrtf(va[t] + 1e-5f); scl[t] = inv; sft[t] = be[t] - mu[t]*inv; }
  __syncthreads();
  int gid = blockIdx.x*256 + t;
  if (gid >= 256*1001) return;
  int b = gid / 1001, wp = gid % 1001;
  const float* yb = ybn1 + (size_t)b*22000;
  float acc[25];
  #pragma unroll
  for (int p = 0; p < 25; ++p) acc[p] = c2b[p];
  for (int c = 0; c < 22; ++c) {
    for (int kw = 0; kw < 12; ++kw) {
      int wi = wp - 6 + kw;
      if (wi < 0 || wi >= 1000) continue;
      float v = yb[c*1000 + wi];
      #pragma unroll
      for (int p = 0; p < 25; ++p) acc[p] += v * w[p*264 + c*12 + kw];
    }
  }
  float* sb = sig + (size_t)b*25025 + wp;
  #pragma unroll
  for (int p = 0; p < 25; ++p) sb[p*1001] = acc[p]*scl[p] + sft[p];
}

// ---------------- signal2spd ----------------
__global__ __launch_bounds__(256) void spd_kernel(const float* __restrict__ sig, float* __restrict__ covs)
{
  __shared__ float s[25*334];
  __shared__ float mean[25];
  __shared__ float cv[625];
  __shared__ float tra;
  int bt = blockIdx.x; int b = bt/3, ep = bt%3;
  int off = ep*334;
  int Lp = (ep < 2) ? 334 : 333;
  int t = threadIdx.x;
  const float* sb = sig + (size_t)b*25025;
  for (int e = t; e < 25*Lp; e += 256) { int c = e / Lp, tt = e % Lp; s[c*334 + tt] = sb[c*1001 + off + tt]; }
  __syncthreads();
  if (t < 25) { float m = 0.f; for (int i = 0; i < Lp; ++i) m += s[t*334 + i]; mean[t] = m / (float)Lp; }
  __syncthreads();
  for (int pi = t; pi < 325; pi += 256) {
    int i = 0, rem = pi;
    while (rem >= 25 - i) { rem -= 25 - i; ++i; }
    int j = i + rem;
    float mi = mean[i], mj = mean[j], acc = 0.f;
    for (int k = 0; k < Lp; ++k) acc += (s[i*334 + k] - mi) * (s[j*334 + k] - mj);
    float v = acc / (float)(Lp - 1);
    cv[i*25 + j] = v; cv[j*25 + i] = v;
  }
  __syncthreads();
  if (t == 0) { float tr = 0.f; for (int i = 0; i < 25; ++i) tr += cv[i*26]; tra = tr; }
  __syncthreads();
  float inv = 1.f / tra;
  for (int e = t; e < 625; e += 256) {
    int i = e / 25, j = e % 25;
    covs[(size_t)bt*625 + e] = cv[e]*inv + ((i == j) ? 1e-5f : 0.f);
  }
}

// ---------------- build V / K / Q29 ----------------
__global__ __launch_bounds__(64) void build_windows_kernel(
    const float* __restrict__ covs,
    const float* __restrict__ sk0, const float* __restrict__ sk1, const float* __restrict__ sk2, const float* __restrict__ sk3,
    const float* __restrict__ sv0, const float* __restrict__ sv1, const float* __restrict__ sv2, const float* __restrict__ sv3,
    const float* __restrict__ sq3,
    float* __restrict__ Vbuf, float* __restrict__ Kbuf, float* __restrict__ Qbuf)
{
  __shared__ float sSub[625], sSv[625], sTmp[625], sSk[100], sTk[100];
  int bw = blockIdx.x;
  int bt = bw / 30, win = bw % 30;
  int t = threadIdx.x;
  int k, r0, c0;
  const float* sv; const float* sk;
  if (win < 16)      { k = 2; r0 = win/4;        c0 = win%4;        sv = sv0; sk = sk0; }
  else if (win < 25) { k = 3; int u = win-16; r0 = u/3; c0 = u%3;   sv = sv1; sk = sk1; }
  else if (win < 29) { k = 4; int u = win-25; r0 = u/2; c0 = u%2;   sv = sv2; sk = sk2; }
  else               { k = 5; r0 = 0;            c0 = 0;            sv = sv3; sk = sk3; }
  int kk = k*k;
  const float* cov = covs + (size_t)bt*625;
  for (int e = t; e < kk*kk; e += 64) {
    int p = e / kk, q = e % kk;
    int ip = (r0 + p/k)*5 + (c0 + p%k);
    int iq = (r0 + q/k)*5 + (c0 + q%k);
    sSub[p*kk + q] = cov[ip*25 + iq];
  }
  for (int e = t; e < kk*25; e += 64) sSv[e] = sv[e];
  for (int e = t; e < kk*4; e += 64)  sSk[e] = sk[e];
  __syncthreads();
  for (int e = t; e < kk*25; e += 64) {
    int i = e / 25, b = e % 25;
    float acc = 0.f;
    for (int j = 0; j < kk; ++j) acc += sSub[i*kk + j] * sSv[j*25 + b];
    sTmp[e] = acc;
  }
  for (int e = t; e < kk*4; e += 64) {
    int i = e / 4, b = e % 4;
    float acc = 0.f;
    for (int j = 0; j < kk; ++j) acc += sSub[i*kk + j] * sSk[j*4 + b];
    sTk[e] = acc;
  }
  __syncthreads();
  float* Vout = Vbuf + (size_t)bw*625;
  for (int e = t; e < 625; e += 64) {
    int a = e / 25, b = e % 25;
    float acc = 0.f;
    for (int i = 0; i < kk; ++i) acc += sSv[i*25 + a] * sTmp[i*25 + b];
    if (a == b) acc += 4e-6f * (float)(1 + a);
    Vout[e] = acc;
  }
  float* Kout = Kbuf + (size_t)bw*16;
  for (int e = t; e < 16; e += 64) {
    int a = e / 4, b = e % 4;
    float acc = 0.f;
    for (int i = 0; i < kk; ++i) acc += sSk[i*4 + a] * sTk[i*4 + b];
    if (a == b) acc += 2.5e-5f * (float)(1 + a);
    Kout[e] = acc;
  }
  if (win == 29) {
    __syncthreads();
    for (int e = t; e < 100; e += 64) {
      int i = e / 4, b = e % 4;
      float acc = 0.f;
      for (int j = 0; j < 25; ++j) acc += sSub[i*25 + j] * sq3[j*4 + b];
      sTk[e] = acc;
    }
    __syncthreads();
    float* Qout = Qbuf + (size_t)bt*16;
    for (int e = t; e < 16; e += 64) {
      int a = e / 4, b = e % 4;
      float acc = 0.f;
      for (int i = 0; i < 25; ++i) acc += sq3[i*4 + a] * sTk[i*4 + b];
      if (a == b) acc += 2.5e-5f * (float)(1 + a);
      Qout[e] = acc;
    }
  }
}

// ---------------- batched eigh: REGISTER-RESIDENT one-sided Jacobi ----------------
// Lane j owns column j of G (in VGPRs). 2 matrices per wave (lanes 0..NPAD-1
// and 32..32+NPAD-1). Partner-column exchange via ds_bpermute (one inst moves
// both directions of all pairs). No barriers, no LDS in the sweep loop.
// lambda_i = ||g_i|| - SHIFT; M = sum_k f(lambda_k)/||g_k||^2 g_k g_k^T.
// MODE 0: f=log(max(w,1e-9)); MODE 1: f=max(exp(w),1e-4); MODE 2: f=max(w, ln 1e-4)
template<int NDATA, int MODE, int SHIFT>
__global__ __launch_bounds__(64) void eighreg_kernel(float* __restrict__ mats, float* __restrict__ norms_out)
{
  constexpr int NPAD = (NDATA + 1) & ~1;   // 26 / 18
  constexpr int NR   = NPAD - 1;           // rounds per sweep
  constexpr int LDW  = NPAD + 1;           // Gn LDS row stride
  constexpr int NT   = NDATA*(NDATA+1)/2;

  __shared__ float lds[2*NDATA*LDW];       // staging, then Gn
  __shared__ float wvs[64];

  int t = threadIdx.x;
  int half = t >> 5;
  int col  = t & 31;
  int base32 = t & 32;
  float* M = mats + (size_t)blockIdx.x*2*NDATA*NDATA;

  // stage both matrices (coalesced)
  for (int e = t; e < 2*NDATA*NDATA; e += 64) lds[e] = M[e];
  __syncthreads();

  const float* st = lds + half*NDATA*NDATA;
  float own[NDATA];
  float n_own = 0.f;
  #pragma unroll
  for (int r = 0; r < NDATA; ++r) {
    float v = 0.f;
    if (col < NDATA) {
      v = 0.5f*(st[r*NDATA + col] + st[col*NDATA + r]);
      if (r == col) v += (float)SHIFT;
    }
    own[r] = v;
    n_own += v*v;
  }
  __syncthreads();

  for (int sw = 0; sw < 12; ++sw) {
    float relacc = 0.f;
    #pragma unroll 1
    for (int r = 0; r < NR; ++r) {
      // tournament partner of column `col` in round r
      int p2 = 2*r - col;
      p2 += (p2 < 0) ? NR : 0;
      p2 -= (p2 >= NR) ? NR : 0;
      p2 = (col == r) ? (NPAD-1) : p2;
      p2 = (col == NPAD-1) ? r : p2;
      int idx = (base32 + p2) * 4;
      // fetch partner column + dot (bitwise-identical on both partner lanes)
      float y[NDATA];
      float d = 0.f;
      #pragma unroll
      for (int r2 = 0; r2 < NDATA; ++r2) {
        float yv = __int_as_float(__builtin_amdgcn_ds_bpermute(idx, __float_as_int(own[r2])));
        y[r2] = yv;
        d = fmaf(own[r2], yv, d);
      }
      float n_other = __int_as_float(__builtin_amdgcn_ds_bpermute(idx, __float_as_int(n_own)));
      // rotation params (uniform form; partner lanes get exact +-s, same c)
      float ad = fabsf(d);
      float dd = (ad > 1e-36f) ? d : 1e-36f;
      float tau = (n_other - n_own) * 0.5f * __builtin_amdgcn_rcpf(dd);
      float mag = __builtin_amdgcn_rcpf(fabsf(tau) + sqrtf(tau*tau + 1.f));
      float tt = copysignf(mag, tau);
      float c = __builtin_amdgcn_rsqf(tt*tt + 1.f);
      float s = tt * c;
      #pragma unroll
      for (int r2 = 0; r2 < NDATA; ++r2) own[r2] = c*own[r2] - s*y[r2];
      relacc = fmaxf(relacc, d*d * __builtin_amdgcn_rcpf(fmaxf(n_own*n_other, 1e-30f)));
      n_own = c*c*n_own + s*s*n_other - 2.f*c*s*d;
    }
    // exact norm refresh (kills incremental drift)
    float nn = 0.f;
    #pragma unroll
    for (int r2 = 0; r2 < NDATA; ++r2) nn = fmaf(own[r2], own[r2], nn);
    n_own = nn;
    if (sw >= 1 && !__any(relacc >= 9e-10f)) break;
  }

  // weights
  float lam = sqrtf(n_own) - (float)SHIFT;
  float f;
  if (MODE == 0)      f = logf(fmaxf(lam, 1e-9f));
  else if (MODE == 1) f = fmaxf(expf(lam), 1e-4f);
  else                f = fmaxf(lam, -9.210340371976182f);
  wvs[t] = (n_own < 1e-30f) ? 0.f : f * __builtin_amdgcn_rcpf(n_own);

  // write columns to LDS for reconstruct
  float* gn = lds + half*NDATA*LDW;
  if (col < NPAD) {
    #pragma unroll
    for (int r2 = 0; r2 < NDATA; ++r2) gn[r2*LDW + col] = own[r2];
  }
  __syncthreads();

  // M = G diag(w) G^T (triangle, mirrored), per half-wave
  const float* wm = wvs + base32;
  float* Mo = M + half*NDATA*NDATA;
  float nacc = 0.f;
  for (int e = col; e < NT; e += 32) {
    int i = 0, rem = e;
    while (rem >= NDATA - i) { rem -= NDATA - i; ++i; }
    int j = i + rem;
    float acc = 0.f;
    #pragma unroll
    for (int k = 0; k < NDATA; ++k) acc += wm[k]*gn[i*LDW + k]*gn[j*LDW + k];
    Mo[i*NDATA + j] = acc;
    Mo[j*NDATA + i] = acc;
    nacc += (i == j) ? acc*acc : 2.f*acc*acc;
  }
  if (norms_out != nullptr) {
    #pragma unroll
    for (int o = 16; o > 0; o >>= 1) nacc += __shfl_xor(nacc, o);
    if (col == 0) norms_out[blockIdx.x*2 + half] = nacc;
  }
}

// ---------------- per-thread 4x4 eigh -> log + Frobenius^2 ----------------
template<int P, int Q>
__device__ __forceinline__ void rot4(float a[4][4], float u[4][4])
{
  float apq = a[P][Q];
  if (fabsf(apq) < 1e-36f) return;
  float app = a[P][P], aqq = a[Q][Q];
  float tau = (aqq - app) / (2.f*apq);
  float tt = 1.f / (fabsf(tau) + sqrtf(tau*tau + 1.f));
  if (tau < 0.f) tt = -tt;
  float c = 1.f / sqrtf(tt*tt + 1.f), s = tt*c;
  #pragma unroll
  for (int k = 0; k < 4; ++k) { float akp = a[k][P], akq = a[k][Q]; a[k][P] = c*akp - s*akq; a[k][Q] = s*akp + c*akq; }
  #pragma unroll
  for (int k = 0; k < 4; ++k) { float apk = a[P][k], aqk = a[Q][k]; a[P][k] = c*apk - s*aqk; a[Q][k] = s*apk + c*aqk; }
  #pragma unroll
  for (int k = 0; k < 4; ++k) { float ukp = u[k][P], ukq = u[k][Q]; u[k][P] = c*ukp - s*ukq; u[k][Q] = s*ukp + c*ukq; }
}

__global__ __launch_bounds__(256) void eigh4_kernel(float* __restrict__ kmats, float* __restrict__ qmats,
                                                    float* __restrict__ norms)
{
  int idx = blockIdx.x*256 + threadIdx.x;
  if (idx >= 23808) return;
  float* M = (idx < 23040) ? (kmats + (size_t)idx*16) : (qmats + (size_t)(idx - 23040)*16);
  float a[4][4], u[4][4];
  #pragma unroll
  for (int i = 0; i < 4; ++i)
    #pragma unroll
    for (int j = 0; j < 4; ++j) { a[i][j] = 0.5f*(M[i*4+j] + M[j*4+i]); u[i][j] = (i == j) ? 1.f : 0.f; }
  #pragma unroll 1
  for (int sw = 0; sw < 8; ++sw) {
    rot4<0,1>(a,u); rot4<0,2>(a,u); rot4<0,3>(a,u);
    rot4<1,2>(a,u); rot4<1,3>(a,u); rot4<2,3>(a,u);
  }
  float f[4];
  #pragma unroll
  for (int i = 0; i < 4; ++i) f[i] = logf(fmaxf(a[i][i], 1e-9f));
  float nrm = 0.f;
  #pragma unroll
  for (int i = 0; i < 4; ++i)
    #pragma unroll
    for (int j = 0; j < 4; ++j) {
      float acc = 0.f;
      #pragma unroll
      for (int k = 0; k < 4; ++k) acc += u[i][k]*f[k]*u[j][k];
      M[i*4+j] = acc; nrm += acc*acc;
    }
  norms[idx] = nrm;
}

// ---------------- attention 1 (only output row 29) ----------------
__global__ __launch_bounds__(64) void att1_kernel(
    const float* __restrict__ logK, const float* __restrict__ logQ,
    const float* __restrict__ kn, const float* __restrict__ qn,
    const float* __restrict__ logV, float* __restrict__ outlog1)
{
  __shared__ float lq[16];
  __shared__ float sscore[30];
  __shared__ float sp[30];
  int bt = blockIdx.x, t = threadIdx.x;
  if (t < 16) lq[t] = logQ[(size_t)bt*16 + t];
  __syncthreads();
  if (t < 30) {
    const float* lk = logK + ((size_t)bt*30 + t)*16;
    float cr = 0.f;
    #pragma unroll
    for (int e = 0; e < 16; ++e) cr += lk[e]*lq[e];
    float E = fmaxf(kn[bt*30 + t] + qn[bt] - 2.f*cr, 0.f);
    sscore[t] = 1.f/(1.f + log1pf(E));
  }
  __syncthreads();
  float mx = -1e30f;
  for (int i = 0; i < 30; ++i) mx = fmaxf(mx, sscore[i]);
  float sm = 0.f;
  for (int i = 0; i < 30; ++i) sm += expf(sscore[i] - mx);
  if (t < 30) sp[t] = expf(sscore[t] - mx)/sm;
  __syncthreads();
  const float* lv = logV + (size_t)bt*30*625;
  float* outp = outlog1 + (size_t)bt*625;
  for (int e = t; e < 625; e += 64) {
    float acc = 0.f;
    for (int i = 0; i < 30; ++i) acc += sp[i]*lv[(size_t)i*625 + e];
    outp[e] = acc;
  }
}

// ---------------- Q2/K2/V2 = W^T xm W ----------------
__global__ __launch_bounds__(64) void qkv2_kernel(
    const float* __restrict__ xm, const float* __restrict__ mq, const float* __restrict__ mk,
    const float* __restrict__ mv, float* __restrict__ q2, float* __restrict__ k2, float* __restrict__ v2)
{
  __shared__ float sx[625], sw[450], stmp[450];
  int bt = blockIdx.x, t = threadIdx.x;
  for (int e = t; e < 625; e += 64) sx[e] = xm[(size_t)bt*625 + e];
  for (int wi = 0; wi < 3; ++wi) {
    const float* W = (wi == 0) ? mq : (wi == 1) ? mk : mv;
    float* O = ((wi == 0) ? q2 : (wi == 1) ? k2 : v2) + (size_t)bt*324;
    for (int e = t; e < 450; e += 64) sw[e] = W[e];
    __syncthreads();
    for (int e = t; e < 450; e += 64) {
      int i = e / 18, b = e % 18;
      float acc = 0.f;
      for (int j = 0; j < 25; ++j) acc += sx[i*25 + j]*sw[j*18 + b];
      stmp[e] = acc;
    }
    __syncthreads();
    for (int e = t; e < 324; e += 64) {
      int a = e / 18, b = e % 18;
      float acc = 0.f;
      for (int i = 0; i < 25; ++i) acc += sw[i*18 + a]*stmp[i*18 + b];
      O[e] = acc;
    }
    __syncthreads();
  }
}

// ---------------- attention 2 ----------------
__global__ __launch_bounds__(64) void att2_kernel(
    const float* __restrict__ logQ2, const float* __restrict__ logK2, const float* __restrict__ logV2,
    const float* __restrict__ norms, float* __restrict__ outlog2)
{
  __shared__ float S[3][3];
  __shared__ float PT[3][3];
  int b = blockIdx.x, t = threadIdx.x;
  if (t < 9) {
    int i = t / 3, j = t % 3;
    const float* lk = logK2 + ((size_t)b*3 + i)*324;
    const float* lq = logQ2 + ((size_t)b*3 + j)*324;
    float cr = 0.f;
    for (int e = 0; e < 324; ++e) cr += lk[e]*lq[e];
    float E = fmaxf(norms[768 + b*3 + i] + norms[b*3 + j] - 2.f*cr, 0.f);
    S[i][j] = 1.f/(1.f + log1pf(E));
  }
  __syncthreads();
  if (t < 3) {
    float m = fmaxf(S[0][t], fmaxf(S[1][t], S[2][t]));
    float e0 = expf(S[0][t]-m), e1 = expf(S[1][t]-m), e2 = expf(S[2][t]-m);
    float ssum = e0 + e1 + e2;
    PT[t][0] = e0/ssum; PT[t][1] = e1/ssum; PT[t][2] = e2/ssum;
  }
  __syncthreads();
  for (int e = t; e < 324; e += 64) {
    float l0 = logV2[((size_t)b*3 + 0)*324 + e];
    float l1 = logV2[((size_t)b*3 + 1)*324 + e];
    float l2 = logV2[((size_t)b*3 + 2)*324 + e];
    #pragma unroll
    for (int j = 0; j < 3; ++j)
      outlog2[((size_t)b*3 + j)*324 + e] = PT[j][0]*l0 + PT[j][1]*l1 + PT[j][2]*l2;
  }
}

// ---------------- features + linear ----------------
__global__ __launch_bounds__(64) void feat_kernel(
    const float* __restrict__ Lg, const float* __restrict__ lw, const float* __restrict__ lb,
    float* __restrict__ outp)
{
  __shared__ int tri_i[171], tri_j[171];
  int b = blockIdx.x, t = threadIdx.x;
  if (t == 0) { int f = 0; for (int i = 0; i < 18; ++i) for (int j = i; j < 18; ++j) { tri_i[f] = i; tri_j[f] = j; ++f; } }
  __syncthreads();
  float a0 = 0.f, a1 = 0.f, a2 = 0.f, a3 = 0.f;
  const float SQ2 = 1.41421356237309515f;
  for (int f = t; f < 513; f += 64) {
    int tt = f / 171, r = f % 171;
    int i = tri_i[r], j = tri_j[r];
    float coef = (i == j) ? 1.f : SQ2;
    float v = Lg[((size_t)b*3 + tt)*324 + i*18 + j] * coef;
    a0 += v*lw[0*513 + f]; a1 += v*lw[1*513 + f]; a2 += v*lw[2*513 + f]; a3 += v*lw[3*513 + f];
  }
  #pragma unroll
  for (int off = 32; off > 0; off >>= 1) {
    a0 += __shfl_down(a0, off); a1 += __shfl_down(a1, off);
    a2 += __shfl_down(a2, off); a3 += __shfl_down(a3, off);
  }
  if (t == 0) {
    outp[b*4 + 0] = a0 + lb[0]; outp[b*4 + 1] = a1 + lb[1];
    outp[b*4 + 2] = a2 + lb[2]; outp[b*4 + 3] = a3 + lb[3];
  }
}

// ---------------------------------------------------------------------------
extern "C" void kernel_launch(void* const* d_in, const int* in_sizes, int n_in,
                              void* d_out, int out_size, void* d_ws, size_t ws_size,
                              hipStream_t stream)
{
  const float* x    = (const float*)d_in[0];
  const float* c1w  = (const float*)d_in[1];
  const float* c1b  = (const float*)d_in[2];
  const float* bn1g = (const float*)d_in[3];
  const float* bn1b = (const float*)d_in[4];
  const float* bn1m = (const float*)d_in[5];
  const float* bn1v = (const float*)d_in[6];
  const float* c2w  = (const float*)d_in[7];
  const float* c2b  = (const float*)d_in[8];
  const float* bn2g = (const float*)d_in[9];
  const float* bn2b = (const float*)d_in[10];
  const float* bn2m = (const float*)d_in[11];
  const float* bn2v = (const float*)d_in[12];
  const float* sk0  = (const float*)d_in[14];
  const float* sv0  = (const float*)d_in[15];
  const float* sk1  = (const float*)d_in[17];
  const float* sv1  = (const float*)d_in[18];
  const float* sk2  = (const float*)d_in[20];
  const float* sv2  = (const float*)d_in[21];
  const float* sq3  = (const float*)d_in[22];
  const float* sk3  = (const float*)d_in[23];
  const float* sv3  = (const float*)d_in[24];
  const float* mq   = (const float*)d_in[25];
  const float* mk   = (const float*)d_in[26];
  const float* mv   = (const float*)d_in[27];
  const float* lw   = (const float*)d_in[28];
  const float* lb   = (const float*)d_in[29];
  float* outp = (float*)d_out;

  float* ws = (float*)d_ws;
  float* covs = ws;                       // 480000
  float* ybn1 = ws + 480000;              // 5632000
  float* sig  = ws + 6112000;             // 6406400
  float* Vbuf = ws + 480000;              // 14400000 (reuses dead ybn1/sig)
  float* Kbuf = ws + 14880000;            // 368640
  float* Qbuf = ws + 15248640;            // 12288
  float* knb  = ws + 15260928;            // 23808
  float* ol1  = ws + 15284736;            // 480000
  float* qkv2 = ws + 15764736;            // 746496
  float* nrm2 = ws + 16511232;            // 2304
  float* ol2  = ws + 16513536;            // 248832

  conv1_kernel<<<1000, 256, 0, stream>>>(x, c1w, c1b, bn1g, bn1b, bn1m, bn1v, ybn1);
  conv2_kernel<<<1001, 256, 0, stream>>>(ybn1, c2w, c2b, bn2g, bn2b, bn2m, bn2v, sig);
  spd_kernel<<<768, 256, 0, stream>>>(sig, covs);
  build_windows_kernel<<<23040, 64, 0, stream>>>(covs, sk0, sk1, sk2, sk3, sv0, sv1, sv2, sv3, sq3,
                                                 Vbuf, Kbuf, Qbuf);
  eighreg_kernel<25,0,0><<<11520, 64, 0, stream>>>(Vbuf, nullptr);         // logV in place
  eigh4_kernel<<<93, 256, 0, stream>>>(Kbuf, Qbuf, knb);                   // logK/logQ + norms
  att1_kernel<<<768, 64, 0, stream>>>(Kbuf, Qbuf, knb, knb + 23040, Vbuf, ol1);
  eighreg_kernel<25,1,16><<<384, 64, 0, stream>>>(ol1, nullptr);           // xm = rect(exp(.)), shifted
  qkv2_kernel<<<768, 64, 0, stream>>>(ol1, mq, mk, mv, qkv2, qkv2 + 248832, qkv2 + 497664);
  eighreg_kernel<18,0,0><<<1152, 64, 0, stream>>>(qkv2, nrm2);             // logs + norms
  att2_kernel<<<256, 64, 0, stream>>>(qkv2, qkv2 + 248832, qkv2 + 497664, nrm2, ol2);
  eighreg_kernel<18,2,16><<<384, 64, 0, stream>>>(ol2, nullptr);           // Lg, shifted
  feat_kernel<<<256, 64, 0, stream>>>(ol2, lw, lb, outp);
}

// Round 6
// 1427.426 us; speedup vs baseline: 4.0214x; 1.0019x over previous
//
#include <hip/hip_runtime.h>
#include <hip/hip_bf16.h>
#include <math.h>

// ---------------------------------------------------------------------------
// Sizes
//   x: (256,1,22,1000)  conv1 (22,1,22,1) VALID -> (256,22,1,1000)
//   conv2 (25,22,1,12) pad (6,6) -> (256,25,1,1001); sig=(256,25,1001)
//   epochs lens = [334,334,333]; covs: (256,3,25,25); windows m=30
// ---------------------------------------------------------------------------

// ---------------- conv1 + bn1 ----------------
__global__ __launch_bounds__(256) void conv1_kernel(
    const float* __restrict__ x, const float* __restrict__ c1w, const float* __restrict__ c1b,
    const float* __restrict__ g, const float* __restrict__ be, const float* __restrict__ mu,
    const float* __restrict__ va, float* __restrict__ ybn1)
{
  __shared__ float w[484];
  __shared__ float scl[22], sft[22];
  int t = threadIdx.x;
  for (int e = t; e < 484; e += 256) w[e] = c1w[e];
  if (t < 22) { float inv = g[t] / sqrtf(va[t] + 1e-5f); scl[t] = inv; sft[t] = be[t] - mu[t]*inv; }
  __syncthreads();
  int gid = blockIdx.x*256 + t;
  int b = gid / 1000, wp = gid % 1000;
  const float* xb = x + (size_t)b*22000 + wp;
  float acc[22];
  #pragma unroll
  for (int o = 0; o < 22; ++o) acc[o] = c1b[o];
  for (int h = 0; h < 22; ++h) {
    float xv = xb[h*1000];
    #pragma unroll
    for (int o = 0; o < 22; ++o) acc[o] += xv * w[o*22 + h];
  }
  float* yb = ybn1 + (size_t)b*22000 + wp;
  #pragma unroll
  for (int o = 0; o < 22; ++o) yb[o*1000] = acc[o]*scl[o] + sft[o];
}

// ---------------- conv2 + bn2 ----------------
__global__ __launch_bounds__(256) void conv2_kernel(
    const float* __restrict__ ybn1, const float* __restrict__ c2w, const float* __restrict__ c2b,
    const float* __restrict__ g, const float* __restrict__ be, const float* __restrict__ mu,
    const float* __restrict__ va, float* __restrict__ sig)
{
  __shared__ float w[6600];
  __shared__ float scl[25], sft[25];
  int t = threadIdx.x;
  for (int e = t; e < 6600; e += 256) w[e] = c2w[e];
  if (t < 25) { float inv = g[t] / sqrtf(va[t] + 1e-5f); scl[t] = inv; sft[t] = be[t] - mu[t]*inv; }
  __syncthreads();
  int gid = blockIdx.x*256 + t;
  if (gid >= 256*1001) return;
  int b = gid / 1001, wp = gid % 1001;
  const float* yb = ybn1 + (size_t)b*22000;
  float acc[25];
  #pragma unroll
  for (int p = 0; p < 25; ++p) acc[p] = c2b[p];
  for (int c = 0; c < 22; ++c) {
    for (int kw = 0; kw < 12; ++kw) {
      int wi = wp - 6 + kw;
      if (wi < 0 || wi >= 1000) continue;
      float v = yb[c*1000 + wi];
      #pragma unroll
      for (int p = 0; p < 25; ++p) acc[p] += v * w[p*264 + c*12 + kw];
    }
  }
  float* sb = sig + (size_t)b*25025 + wp;
  #pragma unroll
  for (int p = 0; p < 25; ++p) sb[p*1001] = acc[p]*scl[p] + sft[p];
}

// ---------------- signal2spd ----------------
__global__ __launch_bounds__(256) void spd_kernel(const float* __restrict__ sig, float* __restrict__ covs)
{
  __shared__ float s[25*334];
  __shared__ float mean[25];
  __shared__ float cv[625];
  __shared__ float tra;
  int bt = blockIdx.x; int b = bt/3, ep = bt%3;
  int off = ep*334;
  int Lp = (ep < 2) ? 334 : 333;
  int t = threadIdx.x;
  const float* sb = sig + (size_t)b*25025;
  for (int e = t; e < 25*Lp; e += 256) { int c = e / Lp, tt = e % Lp; s[c*334 + tt] = sb[c*1001 + off + tt]; }
  __syncthreads();
  if (t < 25) { float m = 0.f; for (int i = 0; i < Lp; ++i) m += s[t*334 + i]; mean[t] = m / (float)Lp; }
  __syncthreads();
  for (int pi = t; pi < 325; pi += 256) {
    int i = 0, rem = pi;
    while (rem >= 25 - i) { rem -= 25 - i; ++i; }
    int j = i + rem;
    float mi = mean[i], mj = mean[j], acc = 0.f;
    for (int k = 0; k < Lp; ++k) acc += (s[i*334 + k] - mi) * (s[j*334 + k] - mj);
    float v = acc / (float)(Lp - 1);
    cv[i*25 + j] = v; cv[j*25 + i] = v;
  }
  __syncthreads();
  if (t == 0) { float tr = 0.f; for (int i = 0; i < 25; ++i) tr += cv[i*26]; tra = tr; }
  __syncthreads();
  float inv = 1.f / tra;
  for (int e = t; e < 625; e += 256) {
    int i = e / 25, j = e % 25;
    covs[(size_t)bt*625 + e] = cv[e]*inv + ((i == j) ? 1e-5f : 0.f);
  }
}

// ---------------- build V / K / Q29 ----------------
__global__ __launch_bounds__(64) void build_windows_kernel(
    const float* __restrict__ covs,
    const float* __restrict__ sk0, const float* __restrict__ sk1, const float* __restrict__ sk2, const float* __restrict__ sk3,
    const float* __restrict__ sv0, const float* __restrict__ sv1, const float* __restrict__ sv2, const float* __restrict__ sv3,
    const float* __restrict__ sq3,
    float* __restrict__ Vbuf, float* __restrict__ Kbuf, float* __restrict__ Qbuf)
{
  __shared__ float sSub[625], sSv[625], sTmp[625], sSk[100], sTk[100];
  int bw = blockIdx.x;
  int bt = bw / 30, win = bw % 30;
  int t = threadIdx.x;
  int k, r0, c0;
  const float* sv; const float* sk;
  if (win < 16)      { k = 2; r0 = win/4;        c0 = win%4;        sv = sv0; sk = sk0; }
  else if (win < 25) { k = 3; int u = win-16; r0 = u/3; c0 = u%3;   sv = sv1; sk = sk1; }
  else if (win < 29) { k = 4; int u = win-25; r0 = u/2; c0 = u%2;   sv = sv2; sk = sk2; }
  else               { k = 5; r0 = 0;            c0 = 0;            sv = sv3; sk = sk3; }
  int kk = k*k;
  const float* cov = covs + (size_t)bt*625;
  for (int e = t; e < kk*kk; e += 64) {
    int p = e / kk, q = e % kk;
    int ip = (r0 + p/k)*5 + (c0 + p%k);
    int iq = (r0 + q/k)*5 + (c0 + q%k);
    sSub[p*kk + q] = cov[ip*25 + iq];
  }
  for (int e = t; e < kk*25; e += 64) sSv[e] = sv[e];
  for (int e = t; e < kk*4; e += 64)  sSk[e] = sk[e];
  __syncthreads();
  for (int e = t; e < kk*25; e += 64) {
    int i = e / 25, b = e % 25;
    float acc = 0.f;
    for (int j = 0; j < kk; ++j) acc += sSub[i*kk + j] * sSv[j*25 + b];
    sTmp[e] = acc;
  }
  for (int e = t; e < kk*4; e += 64) {
    int i = e / 4, b = e % 4;
    float acc = 0.f;
    for (int j = 0; j < kk; ++j) acc += sSub[i*kk + j] * sSk[j*4 + b];
    sTk[e] = acc;
  }
  __syncthreads();
  float* Vout = Vbuf + (size_t)bw*625;
  for (int e = t; e < 625; e += 64) {
    int a = e / 25, b = e % 25;
    float acc = 0.f;
    for (int i = 0; i < kk; ++i) acc += sSv[i*25 + a] * sTmp[i*25 + b];
    if (a == b) acc += 4e-6f * (float)(1 + a);
    Vout[e] = acc;
  }
  float* Kout = Kbuf + (size_t)bw*16;
  for (int e = t; e < 16; e += 64) {
    int a = e / 4, b = e % 4;
    float acc = 0.f;
    for (int i = 0; i < kk; ++i) acc += sSk[i*4 + a] * sTk[i*4 + b];
    if (a == b) acc += 2.5e-5f * (float)(1 + a);
    Kout[e] = acc;
  }
  if (win == 29) {
    __syncthreads();
    for (int e = t; e < 100; e += 64) {
      int i = e / 4, b = e % 4;
      float acc = 0.f;
      for (int j = 0; j < 25; ++j) acc += sSub[i*25 + j] * sq3[j*4 + b];
      sTk[e] = acc;
    }
    __syncthreads();
    float* Qout = Qbuf + (size_t)bt*16;
    for (int e = t; e < 16; e += 64) {
      int a = e / 4, b = e % 4;
      float acc = 0.f;
      for (int i = 0; i < 25; ++i) acc += sq3[i*4 + a] * sTk[i*4 + b];
      if (a == b) acc += 2.5e-5f * (float)(1 + a);
      Qout[e] = acc;
    }
  }
}

// ---------------- batched eigh: REGISTER-RESIDENT one-sided Jacobi (v2) ----------------
// Lane j owns column j of G (in VGPRs). 2 matrices per wave. Partner exchange
// via ds_bpermute. DS-throughput-bound: ~26 ds ops/round is the floor; this
// version cuts ROUNDS (looser relative tol 2e-4) and the per-round VALU
// critical path (5-way split dot chain; cmp/or convergence flag, no rcp).
// MODE 0: f=log(max(w,1e-9)); MODE 1: f=max(exp(w),1e-4); MODE 2: f=max(w, ln 1e-4)
template<int NDATA, int MODE, int SHIFT>
__global__ __launch_bounds__(64) void eighreg_kernel(float* __restrict__ mats, float* __restrict__ norms_out)
{
  constexpr int NPAD = (NDATA + 1) & ~1;   // 26 / 18
  constexpr int NR   = NPAD - 1;           // rounds per sweep
  constexpr int LDW  = NPAD + 1;           // Gn LDS row stride
  constexpr int NT   = NDATA*(NDATA+1)/2;

  __shared__ float lds[2*NDATA*LDW];       // staging, then Gn
  __shared__ float wvs[64];

  int t = threadIdx.x;
  int half = t >> 5;
  int col  = t & 31;
  int base32 = t & 32;
  float* M = mats + (size_t)blockIdx.x*2*NDATA*NDATA;

  // stage both matrices (coalesced)
  for (int e = t; e < 2*NDATA*NDATA; e += 64) lds[e] = M[e];
  __syncthreads();

  const float* st = lds + half*NDATA*NDATA;
  float own[NDATA];
  float n_own = 0.f;
  #pragma unroll
  for (int r = 0; r < NDATA; ++r) {
    float v = 0.f;
    if (col < NDATA) {
      v = 0.5f*(st[r*NDATA + col] + st[col*NDATA + r]);
      if (r == col) v += (float)SHIFT;
    }
    own[r] = v;
    n_own += v*v;
  }
  __syncthreads();

  const float TOL2 = 4e-8f;                // (2e-4)^2 relative
  for (int sw = 0; sw < 12; ++sw) {
    int bad = 0;
    #pragma unroll 1
    for (int r = 0; r < NR; ++r) {
      // tournament partner of column `col` in round r
      int p2 = 2*r - col;
      p2 += (p2 < 0) ? NR : 0;
      p2 -= (p2 >= NR) ? NR : 0;
      p2 = (col == r) ? (NPAD-1) : p2;
      p2 = (col == NPAD-1) ? r : p2;
      int idx = (base32 + p2) * 4;
      // fetch partner column + 5-way split dot (chains independent)
      float y[NDATA];
      float d0 = 0.f, d1 = 0.f, d2 = 0.f, d3 = 0.f, d4 = 0.f;
      #pragma unroll
      for (int r2 = 0; r2 < NDATA; ++r2) {
        float yv = __int_as_float(__builtin_amdgcn_ds_bpermute(idx, __float_as_int(own[r2])));
        y[r2] = yv;
        float pr = own[r2]*yv;
        if      (r2 % 5 == 0) d0 += pr;
        else if (r2 % 5 == 1) d1 += pr;
        else if (r2 % 5 == 2) d2 += pr;
        else if (r2 % 5 == 3) d3 += pr;
        else                  d4 += pr;
      }
      float d = ((d0 + d1) + (d2 + d3)) + d4;
      float n_other = __int_as_float(__builtin_amdgcn_ds_bpermute(idx, __float_as_int(n_own)));
      // rotation params (bitwise-identical on both partner lanes)
      float ad = fabsf(d);
      float dd = (ad > 1e-36f) ? d : 1e-36f;
      float tau = (n_other - n_own) * 0.5f * __builtin_amdgcn_rcpf(dd);
      float mag = __builtin_amdgcn_rcpf(fabsf(tau) + sqrtf(tau*tau + 1.f));
      float tt = copysignf(mag, tau);
      float c = __builtin_amdgcn_rsqf(tt*tt + 1.f);
      float s = tt * c;
      #pragma unroll
      for (int r2 = 0; r2 < NDATA; ++r2) own[r2] = c*own[r2] - s*y[r2];
      bad |= (d*d > TOL2 * n_own * n_other) ? 1 : 0;
      n_own = c*c*n_own + s*s*n_other - 2.f*c*s*d;
    }
    // exact norm refresh (kills incremental drift), split chains
    {
      float n0 = 0.f, n1 = 0.f, n2 = 0.f, n3 = 0.f, n4 = 0.f;
      #pragma unroll
      for (int r2 = 0; r2 < NDATA; ++r2) {
        float pr = own[r2]*own[r2];
        if      (r2 % 5 == 0) n0 += pr;
        else if (r2 % 5 == 1) n1 += pr;
        else if (r2 % 5 == 2) n2 += pr;
        else if (r2 % 5 == 3) n3 += pr;
        else                  n4 += pr;
      }
      n_own = ((n0 + n1) + (n2 + n3)) + n4;
    }
    if (sw >= 1 && !__any(bad)) break;
  }

  // weights
  float lam = sqrtf(n_own) - (float)SHIFT;
  float f;
  if (MODE == 0)      f = logf(fmaxf(lam, 1e-9f));
  else if (MODE == 1) f = fmaxf(expf(lam), 1e-4f);
  else                f = fmaxf(lam, -9.210340371976182f);
  wvs[t] = (n_own < 1e-30f) ? 0.f : f * __builtin_amdgcn_rcpf(n_own);

  // write columns to LDS for reconstruct
  float* gn = lds + half*NDATA*LDW;
  if (col < NPAD) {
    #pragma unroll
    for (int r2 = 0; r2 < NDATA; ++r2) gn[r2*LDW + col] = own[r2];
  }
  __syncthreads();

  // M = G diag(w) G^T (triangle, mirrored), per half-wave
  const float* wm = wvs + base32;
  float* Mo = M + half*NDATA*NDATA;
  float nacc = 0.f;
  for (int e = col; e < NT; e += 32) {
    int i = 0, rem = e;
    while (rem >= NDATA - i) { rem -= NDATA - i; ++i; }
    int j = i + rem;
    float acc = 0.f;
    #pragma unroll
    for (int k = 0; k < NDATA; ++k) acc += wm[k]*gn[i*LDW + k]*gn[j*LDW + k];
    Mo[i*NDATA + j] = acc;
    Mo[j*NDATA + i] = acc;
    nacc += (i == j) ? acc*acc : 2.f*acc*acc;
  }
  if (norms_out != nullptr) {
    #pragma unroll
    for (int o = 16; o > 0; o >>= 1) nacc += __shfl_xor(nacc, o);
    if (col == 0) norms_out[blockIdx.x*2 + half] = nacc;
  }
}

// ---------------- per-thread 4x4 eigh -> log + Frobenius^2 ----------------
template<int P, int Q>
__device__ __forceinline__ void rot4(float a[4][4], float u[4][4])
{
  float apq = a[P][Q];
  if (fabsf(apq) < 1e-36f) return;
  float app = a[P][P], aqq = a[Q][Q];
  float tau = (aqq - app) / (2.f*apq);
  float tt = 1.f / (fabsf(tau) + sqrtf(tau*tau + 1.f));
  if (tau < 0.f) tt = -tt;
  float c = 1.f / sqrtf(tt*tt + 1.f), s = tt*c;
  #pragma unroll
  for (int k = 0; k < 4; ++k) { float akp = a[k][P], akq = a[k][Q]; a[k][P] = c*akp - s*akq; a[k][Q] = s*akp + c*akq; }
  #pragma unroll
  for (int k = 0; k < 4; ++k) { float apk = a[P][k], aqk = a[Q][k]; a[P][k] = c*apk - s*aqk; a[Q][k] = s*apk + c*aqk; }
  #pragma unroll
  for (int k = 0; k < 4; ++k) { float ukp = u[k][P], ukq = u[k][Q]; u[k][P] = c*ukp - s*ukq; u[k][Q] = s*ukp + c*ukq; }
}

__global__ __launch_bounds__(256) void eigh4_kernel(float* __restrict__ kmats, float* __restrict__ qmats,
                                                    float* __restrict__ norms)
{
  int idx = blockIdx.x*256 + threadIdx.x;
  if (idx >= 23808) return;
  float* M = (idx < 23040) ? (kmats + (size_t)idx*16) : (qmats + (size_t)(idx - 23040)*16);
  float a[4][4], u[4][4];
  #pragma unroll
  for (int i = 0; i < 4; ++i)
    #pragma unroll
    for (int j = 0; j < 4; ++j) { a[i][j] = 0.5f*(M[i*4+j] + M[j*4+i]); u[i][j] = (i == j) ? 1.f : 0.f; }
  #pragma unroll 1
  for (int sw = 0; sw < 8; ++sw) {
    rot4<0,1>(a,u); rot4<0,2>(a,u); rot4<0,3>(a,u);
    rot4<1,2>(a,u); rot4<1,3>(a,u); rot4<2,3>(a,u);
  }
  float f[4];
  #pragma unroll
  for (int i = 0; i < 4; ++i) f[i] = logf(fmaxf(a[i][i], 1e-9f));
  float nrm = 0.f;
  #pragma unroll
  for (int i = 0; i < 4; ++i)
    #pragma unroll
    for (int j = 0; j < 4; ++j) {
      float acc = 0.f;
      #pragma unroll
      for (int k = 0; k < 4; ++k) acc += u[i][k]*f[k]*u[j][k];
      M[i*4+j] = acc; nrm += acc*acc;
    }
  norms[idx] = nrm;
}

// ---------------- attention 1 (only output row 29) ----------------
__global__ __launch_bounds__(64) void att1_kernel(
    const float* __restrict__ logK, const float* __restrict__ logQ,
    const float* __restrict__ kn, const float* __restrict__ qn,
    const float* __restrict__ logV, float* __restrict__ outlog1)
{
  __shared__ float lq[16];
  __shared__ float sscore[30];
  __shared__ float sp[30];
  int bt = blockIdx.x, t = threadIdx.x;
  if (t < 16) lq[t] = logQ[(size_t)bt*16 + t];
  __syncthreads();
  if (t < 30) {
    const float* lk = logK + ((size_t)bt*30 + t)*16;
    float cr = 0.f;
    #pragma unroll
    for (int e = 0; e < 16; ++e) cr += lk[e]*lq[e];
    float E = fmaxf(kn[bt*30 + t] + qn[bt] - 2.f*cr, 0.f);
    sscore[t] = 1.f/(1.f + log1pf(E));
  }
  __syncthreads();
  float mx = -1e30f;
  for (int i = 0; i < 30; ++i) mx = fmaxf(mx, sscore[i]);
  float sm = 0.f;
  for (int i = 0; i < 30; ++i) sm += expf(sscore[i] - mx);
  if (t < 30) sp[t] = expf(sscore[t] - mx)/sm;
  __syncthreads();
  const float* lv = logV + (size_t)bt*30*625;
  float* outp = outlog1 + (size_t)bt*625;
  for (int e = t; e < 625; e += 64) {
    float acc = 0.f;
    for (int i = 0; i < 30; ++i) acc += sp[i]*lv[(size_t)i*625 + e];
    outp[e] = acc;
  }
}

// ---------------- Q2/K2/V2 = W^T xm W ----------------
__global__ __launch_bounds__(64) void qkv2_kernel(
    const float* __restrict__ xm, const float* __restrict__ mq, const float* __restrict__ mk,
    const float* __restrict__ mv, float* __restrict__ q2, float* __restrict__ k2, float* __restrict__ v2)
{
  __shared__ float sx[625], sw[450], stmp[450];
  int bt = blockIdx.x, t = threadIdx.x;
  for (int e = t; e < 625; e += 64) sx[e] = xm[(size_t)bt*625 + e];
  for (int wi = 0; wi < 3; ++wi) {
    const float* W = (wi == 0) ? mq : (wi == 1) ? mk : mv;
    float* O = ((wi == 0) ? q2 : (wi == 1) ? k2 : v2) + (size_t)bt*324;
    for (int e = t; e < 450; e += 64) sw[e] = W[e];
    __syncthreads();
    for (int e = t; e < 450; e += 64) {
      int i = e / 18, b = e % 18;
      float acc = 0.f;
      for (int j = 0; j < 25; ++j) acc += sx[i*25 + j]*sw[j*18 + b];
      stmp[e] = acc;
    }
    __syncthreads();
    for (int e = t; e < 324; e += 64) {
      int a = e / 18, b = e % 18;
      float acc = 0.f;
      for (int i = 0; i < 25; ++i) acc += sw[i*18 + a]*stmp[i*18 + b];
      O[e] = acc;
    }
    __syncthreads();
  }
}

// ---------------- attention 2 ----------------
__global__ __launch_bounds__(64) void att2_kernel(
    const float* __restrict__ logQ2, const float* __restrict__ logK2, const float* __restrict__ logV2,
    const float* __restrict__ norms, float* __restrict__ outlog2)
{
  __shared__ float S[3][3];
  __shared__ float PT[3][3];
  int b = blockIdx.x, t = threadIdx.x;
  if (t < 9) {
    int i = t / 3, j = t % 3;
    const float* lk = logK2 + ((size_t)b*3 + i)*324;
    const float* lq = logQ2 + ((size_t)b*3 + j)*324;
    float cr = 0.f;
    for (int e = 0; e < 324; ++e) cr += lk[e]*lq[e];
    float E = fmaxf(norms[768 + b*3 + i] + norms[b*3 + j] - 2.f*cr, 0.f);
    S[i][j] = 1.f/(1.f + log1pf(E));
  }
  __syncthreads();
  if (t < 3) {
    float m = fmaxf(S[0][t], fmaxf(S[1][t], S[2][t]));
    float e0 = expf(S[0][t]-m), e1 = expf(S[1][t]-m), e2 = expf(S[2][t]-m);
    float ssum = e0 + e1 + e2;
    PT[t][0] = e0/ssum; PT[t][1] = e1/ssum; PT[t][2] = e2/ssum;
  }
  __syncthreads();
  for (int e = t; e < 324; e += 64) {
    float l0 = logV2[((size_t)b*3 + 0)*324 + e];
    float l1 = logV2[((size_t)b*3 + 1)*324 + e];
    float l2 = logV2[((size_t)b*3 + 2)*324 + e];
    #pragma unroll
    for (int j = 0; j < 3; ++j)
      outlog2[((size_t)b*3 + j)*324 + e] = PT[j][0]*l0 + PT[j][1]*l1 + PT[j][2]*l2;
  }
}

// ---------------- features + linear ----------------
__global__ __launch_bounds__(64) void feat_kernel(
    const float* __restrict__ Lg, const float* __restrict__ lw, const float* __restrict__ lb,
    float* __restrict__ outp)
{
  __shared__ int tri_i[171], tri_j[171];
  int b = blockIdx.x, t = threadIdx.x;
  if (t == 0) { int f = 0; for (int i = 0; i < 18; ++i) for (int j = i; j < 18; ++j) { tri_i[f] = i; tri_j[f] = j; ++f; } }
  __syncthreads();
  float a0 = 0.f, a1 = 0.f, a2 = 0.f, a3 = 0.f;
  const float SQ2 = 1.41421356237309515f;
  for (int f = t; f < 513; f += 64) {
    int tt = f / 171, r = f % 171;
    int i = tri_i[r], j = tri_j[r];
    float coef = (i == j) ? 1.f : SQ2;
    float v = Lg[((size_t)b*3 + tt)*324 + i*18 + j] * coef;
    a0 += v*lw[0*513 + f]; a1 += v*lw[1*513 + f]; a2 += v*lw[2*513 + f]; a3 += v*lw[3*513 + f];
  }
  #pragma unroll
  for (int off = 32; off > 0; off >>= 1) {
    a0 += __shfl_down(a0, off); a1 += __shfl_down(a1, off);
    a2 += __shfl_down(a2, off); a3 += __shfl_down(a3, off);
  }
  if (t == 0) {
    outp[b*4 + 0] = a0 + lb[0]; outp[b*4 + 1] = a1 + lb[1];
    outp[b*4 + 2] = a2 + lb[2]; outp[b*4 + 3] = a3 + lb[3];
  }
}

// ---------------------------------------------------------------------------
extern "C" void kernel_launch(void* const* d_in, const int* in_sizes, int n_in,
                              void* d_out, int out_size, void* d_ws, size_t ws_size,
                              hipStream_t stream)
{
  const float* x    = (const float*)d_in[0];
  const float* c1w  = (const float*)d_in[1];
  const float* c1b  = (const float*)d_in[2];
  const float* bn1g = (const float*)d_in[3];
  const float* bn1b = (const float*)d_in[4];
  const float* bn1m = (const float*)d_in[5];
  const float* bn1v = (const float*)d_in[6];
  const float* c2w  = (const float*)d_in[7];
  const float* c2b  = (const float*)d_in[8];
  const float* bn2g = (const float*)d_in[9];
  const float* bn2b = (const float*)d_in[10];
  const float* bn2m = (const float*)d_in[11];
  const float* bn2v = (const float*)d_in[12];
  const float* sk0  = (const float*)d_in[14];
  const float* sv0  = (const float*)d_in[15];
  const float* sk1  = (const float*)d_in[17];
  const float* sv1  = (const float*)d_in[18];
  const float* sk2  = (const float*)d_in[20];
  const float* sv2  = (const float*)d_in[21];
  const float* sq3  = (const float*)d_in[22];
  const float* sk3  = (const float*)d_in[23];
  const float* sv3  = (const float*)d_in[24];
  const float* mq   = (const float*)d_in[25];
  const float* mk   = (const float*)d_in[26];
  const float* mv   = (const float*)d_in[27];
  const float* lw   = (const float*)d_in[28];
  const float* lb   = (const float*)d_in[29];
  float* outp = (float*)d_out;

  float* ws = (float*)d_ws;
  float* covs = ws;                       // 480000
  float* ybn1 = ws + 480000;              // 5632000
  float* sig  = ws + 6112000;             // 6406400
  float* Vbuf = ws + 480000;              // 14400000 (reuses dead ybn1/sig)
  float* Kbuf = ws + 14880000;            // 368640
  float* Qbuf = ws + 15248640;            // 12288
  float* knb  = ws + 15260928;            // 23808
  float* ol1  = ws + 15284736;            // 480000
  float* qkv2 = ws + 15764736;            // 746496
  float* nrm2 = ws + 16511232;            // 2304
  float* ol2  = ws + 16513536;            // 248832

  conv1_kernel<<<1000, 256, 0, stream>>>(x, c1w, c1b, bn1g, bn1b, bn1m, bn1v, ybn1);
  conv2_kernel<<<1001, 256, 0, stream>>>(ybn1, c2w, c2b, bn2g, bn2b, bn2m, bn2v, sig);
  spd_kernel<<<768, 256, 0, stream>>>(sig, covs);
  build_windows_kernel<<<23040, 64, 0, stream>>>(covs, sk0, sk1, sk2, sk3, sv0, sv1, sv2, sv3, sq3,
                                                 Vbuf, Kbuf, Qbuf);
  eighreg_kernel<25,0,0><<<11520, 64, 0, stream>>>(Vbuf, nullptr);         // logV in place
  eigh4_kernel<<<93, 256, 0, stream>>>(Kbuf, Qbuf, knb);                   // logK/logQ + norms
  att1_kernel<<<768, 64, 0, stream>>>(Kbuf, Qbuf, knb, knb + 23040, Vbuf, ol1);
  eighreg_kernel<25,1,16><<<384, 64, 0, stream>>>(ol1, nullptr);           // xm = rect(exp(.)), shifted
  qkv2_kernel<<<768, 64, 0, stream>>>(ol1, mq, mk, mv, qkv2, qkv2 + 248832, qkv2 + 497664);
  eighreg_kernel<18,0,0><<<1152, 64, 0, stream>>>(qkv2, nrm2);             // logs + norms
  att2_kernel<<<256, 64, 0, stream>>>(qkv2, qkv2 + 248832, qkv2 + 497664, nrm2, ol2);
  eighreg_kernel<18,2,16><<<384, 64, 0, stream>>>(ol2, nullptr);           // Lg, shifted
  feat_kernel<<<256, 64, 0, stream>>>(ol2, lw, lb, outp);
}

// Round 11
// 1371.686 us; speedup vs baseline: 4.1848x; 1.0406x over previous
//
#include <hip/hip_runtime.h>
#include <hip/hip_bf16.h>
#include <math.h>

// ---------------------------------------------------------------------------
// Sizes
//   x: (256,1,22,1000)  conv1 (22,1,22,1) VALID -> (256,22,1,1000)
//   conv2 (25,22,1,12) pad (6,6) -> (256,25,1,1001); sig=(256,25,1001)
//   epochs lens = [334,334,333]; covs: (256,3,25,25); windows m=30
// ---------------------------------------------------------------------------

// ---------------- conv1 + bn1 ----------------
__global__ __launch_bounds__(256) void conv1_kernel(
    const float* __restrict__ x, const float* __restrict__ c1w, const float* __restrict__ c1b,
    const float* __restrict__ g, const float* __restrict__ be, const float* __restrict__ mu,
    const float* __restrict__ va, float* __restrict__ ybn1)
{
  __shared__ float w[484];
  __shared__ float scl[22], sft[22];
  int t = threadIdx.x;
  for (int e = t; e < 484; e += 256) w[e] = c1w[e];
  if (t < 22) { float inv = g[t] / sqrtf(va[t] + 1e-5f); scl[t] = inv; sft[t] = be[t] - mu[t]*inv; }
  __syncthreads();
  int gid = blockIdx.x*256 + t;
  int b = gid / 1000, wp = gid % 1000;
  const float* xb = x + (size_t)b*22000 + wp;
  float acc[22];
  #pragma unroll
  for (int o = 0; o < 22; ++o) acc[o] = c1b[o];
  for (int h = 0; h < 22; ++h) {
    float xv = xb[h*1000];
    #pragma unroll
    for (int o = 0; o < 22; ++o) acc[o] += xv * w[o*22 + h];
  }
  float* yb = ybn1 + (size_t)b*22000 + wp;
  #pragma unroll
  for (int o = 0; o < 22; ++o) yb[o*1000] = acc[o]*scl[o] + sft[o];
}

// ---------------- conv2 + bn2 ----------------
__global__ __launch_bounds__(256) void conv2_kernel(
    const float* __restrict__ ybn1, const float* __restrict__ c2w, const float* __restrict__ c2b,
    const float* __restrict__ g, const float* __restrict__ be, const float* __restrict__ mu,
    const float* __restrict__ va, float* __restrict__ sig)
{
  __shared__ float w[6600];
  __shared__ float scl[25], sft[25];
  int t = threadIdx.x;
  for (int e = t; e < 6600; e += 256) w[e] = c2w[e];
  if (t < 25) { float inv = g[t] / sqrtf(va[t] + 1e-5f); scl[t] = inv; sft[t] = be[t] - mu[t]*inv; }
  __syncthreads();
  int gid = blockIdx.x*256 + t;
  if (gid >= 256*1001) return;
  int b = gid / 1001, wp = gid % 1001;
  const float* yb = ybn1 + (size_t)b*22000;
  float acc[25];
  #pragma unroll
  for (int p = 0; p < 25; ++p) acc[p] = c2b[p];
  for (int c = 0; c < 22; ++c) {
    for (int kw = 0; kw < 12; ++kw) {
      int wi = wp - 6 + kw;
      if (wi < 0 || wi >= 1000) continue;
      float v = yb[c*1000 + wi];
      #pragma unroll
      for (int p = 0; p < 25; ++p) acc[p] += v * w[p*264 + c*12 + kw];
    }
  }
  float* sb = sig + (size_t)b*25025 + wp;
  #pragma unroll
  for (int p = 0; p < 25; ++p) sb[p*1001] = acc[p]*scl[p] + sft[p];
}

// ---------------- signal2spd ----------------
__global__ __launch_bounds__(256) void spd_kernel(const float* __restrict__ sig, float* __restrict__ covs)
{
  __shared__ float s[25*334];
  __shared__ float mean[25];
  __shared__ float cv[625];
  __shared__ float tra;
  int bt = blockIdx.x; int b = bt/3, ep = bt%3;
  int off = ep*334;
  int Lp = (ep < 2) ? 334 : 333;
  int t = threadIdx.x;
  const float* sb = sig + (size_t)b*25025;
  for (int e = t; e < 25*Lp; e += 256) { int c = e / Lp, tt = e % Lp; s[c*334 + tt] = sb[c*1001 + off + tt]; }
  __syncthreads();
  if (t < 25) { float m = 0.f; for (int i = 0; i < Lp; ++i) m += s[t*334 + i]; mean[t] = m / (float)Lp; }
  __syncthreads();
  for (int pi = t; pi < 325; pi += 256) {
    int i = 0, rem = pi;
    while (rem >= 25 - i) { rem -= 25 - i; ++i; }
    int j = i + rem;
    float mi = mean[i], mj = mean[j], acc = 0.f;
    for (int k = 0; k < Lp; ++k) acc += (s[i*334 + k] - mi) * (s[j*334 + k] - mj);
    float v = acc / (float)(Lp - 1);
    cv[i*25 + j] = v; cv[j*25 + i] = v;
  }
  __syncthreads();
  if (t == 0) { float tr = 0.f; for (int i = 0; i < 25; ++i) tr += cv[i*26]; tra = tr; }
  __syncthreads();
  float inv = 1.f / tra;
  for (int e = t; e < 625; e += 256) {
    int i = e / 25, j = e % 25;
    covs[(size_t)bt*625 + e] = cv[e]*inv + ((i == j) ? 1e-5f : 0.f);
  }
}

// ---------------- build V / K / Q29 ----------------
__global__ __launch_bounds__(64) void build_windows_kernel(
    const float* __restrict__ covs,
    const float* __restrict__ sk0, const float* __restrict__ sk1, const float* __restrict__ sk2, const float* __restrict__ sk3,
    const float* __restrict__ sv0, const float* __restrict__ sv1, const float* __restrict__ sv2, const float* __restrict__ sv3,
    const float* __restrict__ sq3,
    float* __restrict__ Vbuf, float* __restrict__ Kbuf, float* __restrict__ Qbuf)
{
  __shared__ float sSub[625], sSv[625], sTmp[625], sSk[100], sTk[100];
  int bw = blockIdx.x;
  int bt = bw / 30, win = bw % 30;
  int t = threadIdx.x;
  int k, r0, c0;
  const float* sv; const float* sk;
  if (win < 16)      { k = 2; r0 = win/4;        c0 = win%4;        sv = sv0; sk = sk0; }
  else if (win < 25) { k = 3; int u = win-16; r0 = u/3; c0 = u%3;   sv = sv1; sk = sk1; }
  else if (win < 29) { k = 4; int u = win-25; r0 = u/2; c0 = u%2;   sv = sv2; sk = sk2; }
  else               { k = 5; r0 = 0;            c0 = 0;            sv = sv3; sk = sk3; }
  int kk = k*k;
  const float* cov = covs + (size_t)bt*625;
  for (int e = t; e < kk*kk; e += 64) {
    int p = e / kk, q = e % kk;
    int ip = (r0 + p/k)*5 + (c0 + p%k);
    int iq = (r0 + q/k)*5 + (c0 + q%k);
    sSub[p*kk + q] = cov[ip*25 + iq];
  }
  for (int e = t; e < kk*25; e += 64) sSv[e] = sv[e];
  for (int e = t; e < kk*4; e += 64)  sSk[e] = sk[e];
  __syncthreads();
  for (int e = t; e < kk*25; e += 64) {
    int i = e / 25, b = e % 25;
    float acc = 0.f;
    for (int j = 0; j < kk; ++j) acc += sSub[i*kk + j] * sSv[j*25 + b];
    sTmp[e] = acc;
  }
  for (int e = t; e < kk*4; e += 64) {
    int i = e / 4, b = e % 4;
    float acc = 0.f;
    for (int j = 0; j < kk; ++j) acc += sSub[i*kk + j] * sSk[j*4 + b];
    sTk[e] = acc;
  }
  __syncthreads();
  float* Vout = Vbuf + (size_t)bw*625;
  for (int e = t; e < 625; e += 64) {
    int a = e / 25, b = e % 25;
    float acc = 0.f;
    for (int i = 0; i < kk; ++i) acc += sSv[i*25 + a] * sTmp[i*25 + b];
    if (a == b) acc += 4e-6f * (float)(1 + a);
    Vout[e] = acc;
  }
  float* Kout = Kbuf + (size_t)bw*16;
  for (int e = t; e < 16; e += 64) {
    int a = e / 4, b = e % 4;
    float acc = 0.f;
    for (int i = 0; i < kk; ++i) acc += sSk[i*4 + a] * sTk[i*4 + b];
    if (a == b) acc += 2.5e-5f * (float)(1 + a);
    Kout[e] = acc;
  }
  if (win == 29) {
    __syncthreads();
    for (int e = t; e < 100; e += 64) {
      int i = e / 4, b = e % 4;
      float acc = 0.f;
      for (int j = 0; j < 25; ++j) acc += sSub[i*25 + j] * sq3[j*4 + b];
      sTk[e] = acc;
    }
    __syncthreads();
    float* Qout = Qbuf + (size_t)bt*16;
    for (int e = t; e < 16; e += 64) {
      int a = e / 4, b = e % 4;
      float acc = 0.f;
      for (int i = 0; i < 25; ++i) acc += sq3[i*4 + a] * sTk[i*4 + b];
      if (a == b) acc += 2.5e-5f * (float)(1 + a);
      Qout[e] = acc;
    }
  }
}

// ---------------- batched eigh: BRENT-LUK one-sided Jacobi, DPP movement ----------------
// Lane rl of each 16-lane row owns BOTH columns of pair rl (registers).
// Rotation fully lane-local. Tournament cycle (b0 fixed):
//   a0->a1->...->a_{p-1}->b_{p-1}->...->b_1->a0
// i.e. A_i <- A_{i-1} (data to HIGHER lanes = DPP row_shr:1, lane i reads i-1)
//      B_i <- B_{i+1} (data to LOWER lanes = DPP row_shl:1, lane i reads i+1)
//      A_0 <- B_1; B_{p-1} <- A_{p-1}; B_0 fixed.
// [Round-10 bugfix: shl/shr were swapped — row_shr delivers lane i-1's value
//  (cf. DPP prefix-scan idiom), row_shl delivers lane i+1's.]
// 4 matrices per wave. Zero DS ops in the sweep loop. Reconstruct
// M = sum w_k g_k g_k^T is order-invariant so final column positions don't matter.
// MODE 0: f=log(max(w,1e-9)); MODE 1: f=max(exp(w),1e-4); MODE 2: f=max(w, ln 1e-4)
__device__ __forceinline__ float dpp_prev(float v) {  // lane i <- lane i-1 (row_shr:1)
  return __int_as_float(__builtin_amdgcn_update_dpp(0, __float_as_int(v), 0x111, 0xF, 0xF, true));
}
__device__ __forceinline__ float dpp_next(float v) {  // lane i <- lane i+1 (row_shl:1)
  return __int_as_float(__builtin_amdgcn_update_dpp(0, __float_as_int(v), 0x101, 0xF, 0xF, true));
}

template<int NDATA, int MODE, int SHIFT>
__global__ __launch_bounds__(64) void eighbl_kernel(float* __restrict__ mats, float* __restrict__ norms_out)
{
  constexpr int ND    = NDATA;
  constexpr int NPAIR = (NDATA+1)/2;     // 13 / 9
  constexpr int NPAD  = 2*NPAIR;         // 26 / 18
  constexpr int NRND  = NPAD-1;          // 25 / 17
  constexpr int NT    = ND*(ND+1)/2;
  constexpr int STG   = 4*ND*ND;
  constexpr int GNS   = 4*NPAD*ND;
  constexpr int LSZ   = (STG > GNS ? STG : GNS);

  __shared__ float lds[LSZ];
  __shared__ float wv[4*NPAD];

  int t = threadIdx.x;
  int rl = t & 15, mat = t >> 4;
  bool act = rl < NPAIR;
  bool is0 = rl == 0;
  bool isL = rl == NPAIR-1;
  float* M = mats + (size_t)blockIdx.x*4*ND*ND;

  // stage 4 matrices (coalesced)
  for (int e = t; e < STG; e += 64) lds[e] = M[e];
  __syncthreads();

  const float* st = lds + mat*ND*ND;
  int cA = rl, cB = rl + NPAIR;
  float a[ND], b[ND];
  float na = 0.f, nb = 0.f;
  #pragma unroll
  for (int i = 0; i < ND; ++i) {
    float va = 0.f, vb = 0.f;
    if (act) {
      va = 0.5f*(st[i*ND + cA] + st[cA*ND + i]);
      if (i == cA) va += (float)SHIFT;
      if (cB < ND) {
        vb = 0.5f*(st[i*ND + cB] + st[cB*ND + i]);
        if (i == cB) vb += (float)SHIFT;
      }
    }
    a[i] = va; b[i] = vb;
    na += va*va; nb += vb*vb;
  }

  const float TOL2 = 4e-8f;              // (2e-4)^2 relative
  for (int sw = 0; sw < 12; ++sw) {
    int bad = 0;
    #pragma unroll 1
    for (int r = 0; r < NRND; ++r) {
      // local pair dot (split chains)
      float d0=0.f,d1=0.f,d2=0.f,d3=0.f,d4=0.f;
      #pragma unroll
      for (int i = 0; i < ND; ++i) {
        float pr = a[i]*b[i];
        if      (i % 5 == 0) d0 += pr;
        else if (i % 5 == 1) d1 += pr;
        else if (i % 5 == 2) d2 += pr;
        else if (i % 5 == 3) d3 += pr;
        else                 d4 += pr;
      }
      float d = ((d0 + d1) + (d2 + d3)) + d4;
      // rotation params (lane-local, computed once per pair)
      float ad = fabsf(d);
      float dd = (ad > 1e-36f) ? d : 1e-36f;
      float tau = (nb - na) * 0.5f * __builtin_amdgcn_rcpf(dd);
      float mag = __builtin_amdgcn_rcpf(fabsf(tau) + sqrtf(tau*tau + 1.f));
      float tt = copysignf(mag, tau);
      float c = __builtin_amdgcn_rsqf(tt*tt + 1.f);
      float s = tt * c;
      // rotate both columns in registers
      #pragma unroll
      for (int i = 0; i < ND; ++i) {
        float ta = a[i];
        a[i] = c*ta - s*b[i];
        b[i] = s*ta + c*b[i];
      }
      float csd = 2.f*c*s*d;
      float nan_ = c*c*na + s*s*nb - csd;
      float nbn_ = s*s*na + c*c*nb + csd;
      bad |= (act && (d*d > TOL2*na*nb)) ? 1 : 0;
      na = nan_; nb = nbn_;
      // movement: A_i<-A_{i-1} (dpp_prev); A_0<-B_1; B_i<-B_{i+1} (dpp_next);
      //           B_last<-A_last; B_0 fixed
      #pragma unroll
      for (int i = 0; i < ND; ++i) {
        float tA = dpp_prev(a[i]);
        float tB = dpp_next(b[i]);
        float ao = a[i];
        a[i] = is0 ? tB : tA;
        b[i] = isL ? ao : (is0 ? b[i] : tB);
      }
      {
        float tA = dpp_prev(na);
        float tB = dpp_next(nb);
        float ao = na;
        na = is0 ? tB : tA;
        nb = isL ? ao : (is0 ? nb : tB);
      }
    }
    // exact norm refresh (kills incremental drift)
    {
      float n0=0.f,n1=0.f,n2=0.f,n3=0.f,n4=0.f;
      float m0=0.f,m1=0.f,m2=0.f,m3=0.f,m4=0.f;
      #pragma unroll
      for (int i = 0; i < ND; ++i) {
        float pa = a[i]*a[i], pb = b[i]*b[i];
        if      (i % 5 == 0) { n0 += pa; m0 += pb; }
        else if (i % 5 == 1) { n1 += pa; m1 += pb; }
        else if (i % 5 == 2) { n2 += pa; m2 += pb; }
        else if (i % 5 == 3) { n3 += pa; m3 += pb; }
        else                 { n4 += pa; m4 += pb; }
      }
      na = ((n0 + n1) + (n2 + n3)) + n4;
      nb = ((m0 + m1) + (m2 + m3)) + m4;
    }
    if (sw >= 1 && !__any(bad)) break;
  }

  // weights w = f(||g|| - SHIFT) / ||g||^2
  float lamA = sqrtf(na) - (float)SHIFT;
  float lamB = sqrtf(nb) - (float)SHIFT;
  float fA, fB;
  if (MODE == 0)      { fA = logf(fmaxf(lamA, 1e-9f));  fB = logf(fmaxf(lamB, 1e-9f)); }
  else if (MODE == 1) { fA = fmaxf(expf(lamA), 1e-4f);  fB = fmaxf(expf(lamB), 1e-4f); }
  else                { fA = fmaxf(lamA, -9.210340371976182f); fB = fmaxf(lamB, -9.210340371976182f); }
  float wA = (na < 1e-30f) ? 0.f : fA * __builtin_amdgcn_rcpf(na);
  float wB = (nb < 1e-30f) ? 0.f : fB * __builtin_amdgcn_rcpf(nb);

  __syncthreads();
  // dump columns to LDS [slot][row] (slot order irrelevant)
  float* gn = lds + mat*NPAD*ND;
  if (act) {
    #pragma unroll
    for (int i = 0; i < ND; ++i) {
      gn[rl*ND + i] = a[i];
      gn[(rl + NPAIR)*ND + i] = b[i];
    }
    wv[mat*NPAD + rl] = wA;
    wv[mat*NPAD + rl + NPAIR] = wB;
  }
  __syncthreads();

  // preload weights into registers (broadcast reads per row)
  float wreg[NPAD];
  #pragma unroll
  for (int k = 0; k < NPAD; ++k) wreg[k] = wv[mat*NPAD + k];

  // M = sum_k w_k g_k g_k^T (triangle, mirrored), 16 lanes per matrix
  float* Mo = M + mat*ND*ND;
  const float* g = lds + mat*NPAD*ND;
  float nacc = 0.f;
  for (int e = rl; e < NT; e += 16) {
    int i = 0, rem = e;
    while (rem >= ND - i) { rem -= ND - i; ++i; }
    int j = i + rem;
    float acc = 0.f;
    #pragma unroll
    for (int k = 0; k < NPAD; ++k) acc += wreg[k] * g[k*ND + i] * g[k*ND + j];
    Mo[i*ND + j] = acc;
    Mo[j*ND + i] = acc;
    nacc += (i == j) ? acc*acc : 2.f*acc*acc;
  }
  if (norms_out != nullptr) {
    nacc += __shfl_xor(nacc, 8);
    nacc += __shfl_xor(nacc, 4);
    nacc += __shfl_xor(nacc, 2);
    nacc += __shfl_xor(nacc, 1);
    if (rl == 0) norms_out[blockIdx.x*4 + mat] = nacc;
  }
}

// ---------------- per-thread 4x4 eigh -> log + Frobenius^2 ----------------
template<int P, int Q>
__device__ __forceinline__ void rot4(float a[4][4], float u[4][4])
{
  float apq = a[P][Q];
  if (fabsf(apq) < 1e-36f) return;
  float app = a[P][P], aqq = a[Q][Q];
  float tau = (aqq - app) / (2.f*apq);
  float tt = 1.f / (fabsf(tau) + sqrtf(tau*tau + 1.f));
  if (tau < 0.f) tt = -tt;
  float c = 1.f / sqrtf(tt*tt + 1.f), s = tt*c;
  #pragma unroll
  for (int k = 0; k < 4; ++k) { float akp = a[k][P], akq = a[k][Q]; a[k][P] = c*akp - s*akq; a[k][Q] = s*akp + c*akq; }
  #pragma unroll
  for (int k = 0; k < 4; ++k) { float apk = a[P][k], aqk = a[Q][k]; a[P][k] = c*apk - s*aqk; a[Q][k] = s*apk + c*aqk; }
  #pragma unroll
  for (int k = 0; k < 4; ++k) { float ukp = u[k][P], ukq = u[k][Q]; u[k][P] = c*ukp - s*ukq; u[k][Q] = s*ukp + c*ukq; }
}

__global__ __launch_bounds__(256) void eigh4_kernel(float* __restrict__ kmats, float* __restrict__ qmats,
                                                    float* __restrict__ norms)
{
  int idx = blockIdx.x*256 + threadIdx.x;
  if (idx >= 23808) return;
  float* M = (idx < 23040) ? (kmats + (size_t)idx*16) : (qmats + (size_t)(idx - 23040)*16);
  float a[4][4], u[4][4];
  #pragma unroll
  for (int i = 0; i < 4; ++i)
    #pragma unroll
    for (int j = 0; j < 4; ++j) { a[i][j] = 0.5f*(M[i*4+j] + M[j*4+i]); u[i][j] = (i == j) ? 1.f : 0.f; }
  #pragma unroll 1
  for (int sw = 0; sw < 8; ++sw) {
    rot4<0,1>(a,u); rot4<0,2>(a,u); rot4<0,3>(a,u);
    rot4<1,2>(a,u); rot4<1,3>(a,u); rot4<2,3>(a,u);
  }
  float f[4];
  #pragma unroll
  for (int i = 0; i < 4; ++i) f[i] = logf(fmaxf(a[i][i], 1e-9f));
  float nrm = 0.f;
  #pragma unroll
  for (int i = 0; i < 4; ++i)
    #pragma unroll
    for (int j = 0; j < 4; ++j) {
      float acc = 0.f;
      #pragma unroll
      for (int k = 0; k < 4; ++k) acc += u[i][k]*f[k]*u[j][k];
      M[i*4+j] = acc; nrm += acc*acc;
    }
  norms[idx] = nrm;
}

// ---------------- attention 1 (only output row 29) ----------------
__global__ __launch_bounds__(64) void att1_kernel(
    const float* __restrict__ logK, const float* __restrict__ logQ,
    const float* __restrict__ kn, const float* __restrict__ qn,
    const float* __restrict__ logV, float* __restrict__ outlog1)
{
  __shared__ float lq[16];
  __shared__ float sscore[30];
  __shared__ float sp[30];
  int bt = blockIdx.x, t = threadIdx.x;
  if (t < 16) lq[t] = logQ[(size_t)bt*16 + t];
  __syncthreads();
  if (t < 30) {
    const float* lk = logK + ((size_t)bt*30 + t)*16;
    float cr = 0.f;
    #pragma unroll
    for (int e = 0; e < 16; ++e) cr += lk[e]*lq[e];
    float E = fmaxf(kn[bt*30 + t] + qn[bt] - 2.f*cr, 0.f);
    sscore[t] = 1.f/(1.f + log1pf(E));
  }
  __syncthreads();
  float mx = -1e30f;
  for (int i = 0; i < 30; ++i) mx = fmaxf(mx, sscore[i]);
  float sm = 0.f;
  for (int i = 0; i < 30; ++i) sm += expf(sscore[i] - mx);
  if (t < 30) sp[t] = expf(sscore[t] - mx)/sm;
  __syncthreads();
  const float* lv = logV + (size_t)bt*30*625;
  float* outp = outlog1 + (size_t)bt*625;
  for (int e = t; e < 625; e += 64) {
    float acc = 0.f;
    for (int i = 0; i < 30; ++i) acc += sp[i]*lv[(size_t)i*625 + e];
    outp[e] = acc;
  }
}

// ---------------- Q2/K2/V2 = W^T xm W ----------------
__global__ __launch_bounds__(64) void qkv2_kernel(
    const float* __restrict__ xm, const float* __restrict__ mq, const float* __restrict__ mk,
    const float* __restrict__ mv, float* __restrict__ q2, float* __restrict__ k2, float* __restrict__ v2)
{
  __shared__ float sx[625], sw[450], stmp[450];
  int bt = blockIdx.x, t = threadIdx.x;
  for (int e = t; e < 625; e += 64) sx[e] = xm[(size_t)bt*625 + e];
  for (int wi = 0; wi < 3; ++wi) {
    const float* W = (wi == 0) ? mq : (wi == 1) ? mk : mv;
    float* O = ((wi == 0) ? q2 : (wi == 1) ? k2 : v2) + (size_t)bt*324;
    for (int e = t; e < 450; e += 64) sw[e] = W[e];
    __syncthreads();
    for (int e = t; e < 450; e += 64) {
      int i = e / 18, b = e % 18;
      float acc = 0.f;
      for (int j = 0; j < 25; ++j) acc += sx[i*25 + j]*sw[j*18 + b];
      stmp[e] = acc;
    }
    __syncthreads();
    for (int e = t; e < 324; e += 64) {
      int a = e / 18, b = e % 18;
      float acc = 0.f;
      for (int i = 0; i < 25; ++i) acc += sw[i*18 + a]*stmp[i*18 + b];
      O[e] = acc;
    }
    __syncthreads();
  }
}

// ---------------- attention 2 ----------------
__global__ __launch_bounds__(64) void att2_kernel(
    const float* __restrict__ logQ2, const float* __restrict__ logK2, const float* __restrict__ logV2,
    const float* __restrict__ norms, float* __restrict__ outlog2)
{
  __shared__ float S[3][3];
  __shared__ float PT[3][3];
  int b = blockIdx.x, t = threadIdx.x;
  if (t < 9) {
    int i = t / 3, j = t % 3;
    const float* lk = logK2 + ((size_t)b*3 + i)*324;
    const float* lq = logQ2 + ((size_t)b*3 + j)*324;
    float cr = 0.f;
    for (int e = 0; e < 324; ++e) cr += lk[e]*lq[e];
    float E = fmaxf(norms[768 + b*3 + i] + norms[b*3 + j] - 2.f*cr, 0.f);
    S[i][j] = 1.f/(1.f + log1pf(E));
  }
  __syncthreads();
  if (t < 3) {
    float m = fmaxf(S[0][t], fmaxf(S[1][t], S[2][t]));
    float e0 = expf(S[0][t]-m), e1 = expf(S[1][t]-m), e2 = expf(S[2][t]-m);
    float ssum = e0 + e1 + e2;
    PT[t][0] = e0/ssum; PT[t][1] = e1/ssum; PT[t][2] = e2/ssum;
  }
  __syncthreads();
  for (int e = t; e < 324; e += 64) {
    float l0 = logV2[((size_t)b*3 + 0)*324 + e];
    float l1 = logV2[((size_t)b*3 + 1)*324 + e];
    float l2 = logV2[((size_t)b*3 + 2)*324 + e];
    #pragma unroll
    for (int j = 0; j < 3; ++j)
      outlog2[((size_t)b*3 + j)*324 + e] = PT[j][0]*l0 + PT[j][1]*l1 + PT[j][2]*l2;
  }
}

// ---------------- features + linear ----------------
__global__ __launch_bounds__(64) void feat_kernel(
    const float* __restrict__ Lg, const float* __restrict__ lw, const float* __restrict__ lb,
    float* __restrict__ outp)
{
  __shared__ int tri_i[171], tri_j[171];
  int b = blockIdx.x, t = threadIdx.x;
  if (t == 0) { int f = 0; for (int i = 0; i < 18; ++i) for (int j = i; j < 18; ++j) { tri_i[f] = i; tri_j[f] = j; ++f; } }
  __syncthreads();
  float a0 = 0.f, a1 = 0.f, a2 = 0.f, a3 = 0.f;
  const float SQ2 = 1.41421356237309515f;
  for (int f = t; f < 513; f += 64) {
    int tt = f / 171, r = f % 171;
    int i = tri_i[r], j = tri_j[r];
    float coef = (i == j) ? 1.f : SQ2;
    float v = Lg[((size_t)b*3 + tt)*324 + i*18 + j] * coef;
    a0 += v*lw[0*513 + f]; a1 += v*lw[1*513 + f]; a2 += v*lw[2*513 + f]; a3 += v*lw[3*513 + f];
  }
  #pragma unroll
  for (int off = 32; off > 0; off >>= 1) {
    a0 += __shfl_down(a0, off); a1 += __shfl_down(a1, off);
    a2 += __shfl_down(a2, off); a3 += __shfl_down(a3, off);
  }
  if (t == 0) {
    outp[b*4 + 0] = a0 + lb[0]; outp[b*4 + 1] = a1 + lb[1];
    outp[b*4 + 2] = a2 + lb[2]; outp[b*4 + 3] = a3 + lb[3];
  }
}

// ---------------------------------------------------------------------------
extern "C" void kernel_launch(void* const* d_in, const int* in_sizes, int n_in,
                              void* d_out, int out_size, void* d_ws, size_t ws_size,
                              hipStream_t stream)
{
  const float* x    = (const float*)d_in[0];
  const float* c1w  = (const float*)d_in[1];
  const float* c1b  = (const float*)d_in[2];
  const float* bn1g = (const float*)d_in[3];
  const float* bn1b = (const float*)d_in[4];
  const float* bn1m = (const float*)d_in[5];
  const float* bn1v = (const float*)d_in[6];
  const float* c2w  = (const float*)d_in[7];
  const float* c2b  = (const float*)d_in[8];
  const float* bn2g = (const float*)d_in[9];
  const float* bn2b = (const float*)d_in[10];
  const float* bn2m = (const float*)d_in[11];
  const float* bn2v = (const float*)d_in[12];
  const float* sk0  = (const float*)d_in[14];
  const float* sv0  = (const float*)d_in[15];
  const float* sk1  = (const float*)d_in[17];
  const float* sv1  = (const float*)d_in[18];
  const float* sk2  = (const float*)d_in[20];
  const float* sv2  = (const float*)d_in[21];
  const float* sq3  = (const float*)d_in[22];
  const float* sk3  = (const float*)d_in[23];
  const float* sv3  = (const float*)d_in[24];
  const float* mq   = (const float*)d_in[25];
  const float* mk   = (const float*)d_in[26];
  const float* mv   = (const float*)d_in[27];
  const float* lw   = (const float*)d_in[28];
  const float* lb   = (const float*)d_in[29];
  float* outp = (float*)d_out;

  float* ws = (float*)d_ws;
  float* covs = ws;                       // 480000
  float* ybn1 = ws + 480000;              // 5632000
  float* sig  = ws + 6112000;             // 6406400
  float* Vbuf = ws + 480000;              // 14400000 (reuses dead ybn1/sig)
  float* Kbuf = ws + 14880000;            // 368640
  float* Qbuf = ws + 15248640;            // 12288
  float* knb  = ws + 15260928;            // 23808
  float* ol1  = ws + 15284736;            // 480000
  float* qkv2 = ws + 15764736;            // 746496
  float* nrm2 = ws + 16511232;            // 2304
  float* ol2  = ws + 16513536;            // 248832

  conv1_kernel<<<1000, 256, 0, stream>>>(x, c1w, c1b, bn1g, bn1b, bn1m, bn1v, ybn1);
  conv2_kernel<<<1001, 256, 0, stream>>>(ybn1, c2w, c2b, bn2g, bn2b, bn2m, bn2v, sig);
  spd_kernel<<<768, 256, 0, stream>>>(sig, covs);
  build_windows_kernel<<<23040, 64, 0, stream>>>(covs, sk0, sk1, sk2, sk3, sv0, sv1, sv2, sv3, sq3,
                                                 Vbuf, Kbuf, Qbuf);
  eighbl_kernel<25,0,0><<<5760, 64, 0, stream>>>(Vbuf, nullptr);           // logV in place
  eigh4_kernel<<<93, 256, 0, stream>>>(Kbuf, Qbuf, knb);                   // logK/logQ + norms
  att1_kernel<<<768, 64, 0, stream>>>(Kbuf, Qbuf, knb, knb + 23040, Vbuf, ol1);
  eighbl_kernel<25,1,16><<<192, 64, 0, stream>>>(ol1, nullptr);            // xm = rect(exp(.)), shifted
  qkv2_kernel<<<768, 64, 0, stream>>>(ol1, mq, mk, mv, qkv2, qkv2 + 248832, qkv2 + 497664);
  eighbl_kernel<18,0,0><<<576, 64, 0, stream>>>(qkv2, nrm2);               // logs + norms
  att2_kernel<<<256, 64, 0, stream>>>(qkv2, qkv2 + 248832, qkv2 + 497664, nrm2, ol2);
  eighbl_kernel<18,2,16><<<192, 64, 0, stream>>>(ol2, nullptr);            // Lg, shifted
  feat_kernel<<<256, 64, 0, stream>>>(ol2, lw, lb, outp);
}

// Round 12
// 1201.067 us; speedup vs baseline: 4.7793x; 1.1421x over previous
//
#include <hip/hip_runtime.h>
#include <hip/hip_bf16.h>
#include <math.h>

// ---------------------------------------------------------------------------
// Sizes
//   x: (256,1,22,1000)  conv1 (22,1,22,1) VALID -> (256,22,1,1000)
//   conv2 (25,22,1,12) pad (6,6) -> (256,25,1,1001); sig=(256,25,1001)
//   epochs lens = [334,334,333]; covs: (256,3,25,25); windows m=30
// ---------------------------------------------------------------------------

// ---------------- conv1 + bn1 ----------------
__global__ __launch_bounds__(256) void conv1_kernel(
    const float* __restrict__ x, const float* __restrict__ c1w, const float* __restrict__ c1b,
    const float* __restrict__ g, const float* __restrict__ be, const float* __restrict__ mu,
    const float* __restrict__ va, float* __restrict__ ybn1)
{
  __shared__ float w[484];
  __shared__ float scl[22], sft[22];
  int t = threadIdx.x;
  for (int e = t; e < 484; e += 256) w[e] = c1w[e];
  if (t < 22) { float inv = g[t] / sqrtf(va[t] + 1e-5f); scl[t] = inv; sft[t] = be[t] - mu[t]*inv; }
  __syncthreads();
  int gid = blockIdx.x*256 + t;
  int b = gid / 1000, wp = gid % 1000;
  const float* xb = x + (size_t)b*22000 + wp;
  float acc[22];
  #pragma unroll
  for (int o = 0; o < 22; ++o) acc[o] = c1b[o];
  for (int h = 0; h < 22; ++h) {
    float xv = xb[h*1000];
    #pragma unroll
    for (int o = 0; o < 22; ++o) acc[o] += xv * w[o*22 + h];
  }
  float* yb = ybn1 + (size_t)b*22000 + wp;
  #pragma unroll
  for (int o = 0; o < 22; ++o) yb[o*1000] = acc[o]*scl[o] + sft[o];
}

// ---------------- conv2 + bn2 ----------------
__global__ __launch_bounds__(256) void conv2_kernel(
    const float* __restrict__ ybn1, const float* __restrict__ c2w, const float* __restrict__ c2b,
    const float* __restrict__ g, const float* __restrict__ be, const float* __restrict__ mu,
    const float* __restrict__ va, float* __restrict__ sig)
{
  __shared__ float w[6600];
  __shared__ float scl[25], sft[25];
  int t = threadIdx.x;
  for (int e = t; e < 6600; e += 256) w[e] = c2w[e];
  if (t < 25) { float inv = g[t] / sqrtf(va[t] + 1e-5f); scl[t] = inv; sft[t] = be[t] - mu[t]*inv; }
  __syncthreads();
  int gid = blockIdx.x*256 + t;
  if (gid >= 256*1001) return;
  int b = gid / 1001, wp = gid % 1001;
  const float* yb = ybn1 + (size_t)b*22000;
  float acc[25];
  #pragma unroll
  for (int p = 0; p < 25; ++p) acc[p] = c2b[p];
  for (int c = 0; c < 22; ++c) {
    for (int kw = 0; kw < 12; ++kw) {
      int wi = wp - 6 + kw;
      if (wi < 0 || wi >= 1000) continue;
      float v = yb[c*1000 + wi];
      #pragma unroll
      for (int p = 0; p < 25; ++p) acc[p] += v * w[p*264 + c*12 + kw];
    }
  }
  float* sb = sig + (size_t)b*25025 + wp;
  #pragma unroll
  for (int p = 0; p < 25; ++p) sb[p*1001] = acc[p]*scl[p] + sft[p];
}

// ---------------- signal2spd ----------------
__global__ __launch_bounds__(256) void spd_kernel(const float* __restrict__ sig, float* __restrict__ covs)
{
  __shared__ float s[25*334];
  __shared__ float mean[25];
  __shared__ float cv[625];
  __shared__ float tra;
  int bt = blockIdx.x; int b = bt/3, ep = bt%3;
  int off = ep*334;
  int Lp = (ep < 2) ? 334 : 333;
  int t = threadIdx.x;
  const float* sb = sig + (size_t)b*25025;
  for (int e = t; e < 25*Lp; e += 256) { int c = e / Lp, tt = e % Lp; s[c*334 + tt] = sb[c*1001 + off + tt]; }
  __syncthreads();
  if (t < 25) { float m = 0.f; for (int i = 0; i < Lp; ++i) m += s[t*334 + i]; mean[t] = m / (float)Lp; }
  __syncthreads();
  for (int pi = t; pi < 325; pi += 256) {
    int i = 0, rem = pi;
    while (rem >= 25 - i) { rem -= 25 - i; ++i; }
    int j = i + rem;
    float mi = mean[i], mj = mean[j], acc = 0.f;
    for (int k = 0; k < Lp; ++k) acc += (s[i*334 + k] - mi) * (s[j*334 + k] - mj);
    float v = acc / (float)(Lp - 1);
    cv[i*25 + j] = v; cv[j*25 + i] = v;
  }
  __syncthreads();
  if (t == 0) { float tr = 0.f; for (int i = 0; i < 25; ++i) tr += cv[i*26]; tra = tr; }
  __syncthreads();
  float inv = 1.f / tra;
  for (int e = t; e < 625; e += 256) {
    int i = e / 25, j = e % 25;
    covs[(size_t)bt*625 + e] = cv[e]*inv + ((i == j) ? 1e-5f : 0.f);
  }
}

// ---------------- build V / K / Q29 ----------------
__global__ __launch_bounds__(64) void build_windows_kernel(
    const float* __restrict__ covs,
    const float* __restrict__ sk0, const float* __restrict__ sk1, const float* __restrict__ sk2, const float* __restrict__ sk3,
    const float* __restrict__ sv0, const float* __restrict__ sv1, const float* __restrict__ sv2, const float* __restrict__ sv3,
    const float* __restrict__ sq3,
    float* __restrict__ Vbuf, float* __restrict__ Kbuf, float* __restrict__ Qbuf)
{
  __shared__ float sSub[625], sSv[625], sTmp[625], sSk[100], sTk[100];
  int bw = blockIdx.x;
  int bt = bw / 30, win = bw % 30;
  int t = threadIdx.x;
  int k, r0, c0;
  const float* sv; const float* sk;
  if (win < 16)      { k = 2; r0 = win/4;        c0 = win%4;        sv = sv0; sk = sk0; }
  else if (win < 25) { k = 3; int u = win-16; r0 = u/3; c0 = u%3;   sv = sv1; sk = sk1; }
  else if (win < 29) { k = 4; int u = win-25; r0 = u/2; c0 = u%2;   sv = sv2; sk = sk2; }
  else               { k = 5; r0 = 0;            c0 = 0;            sv = sv3; sk = sk3; }
  int kk = k*k;
  const float* cov = covs + (size_t)bt*625;
  for (int e = t; e < kk*kk; e += 64) {
    int p = e / kk, q = e % kk;
    int ip = (r0 + p/k)*5 + (c0 + p%k);
    int iq = (r0 + q/k)*5 + (c0 + q%k);
    sSub[p*kk + q] = cov[ip*25 + iq];
  }
  for (int e = t; e < kk*25; e += 64) sSv[e] = sv[e];
  for (int e = t; e < kk*4; e += 64)  sSk[e] = sk[e];
  __syncthreads();
  for (int e = t; e < kk*25; e += 64) {
    int i = e / 25, b = e % 25;
    float acc = 0.f;
    for (int j = 0; j < kk; ++j) acc += sSub[i*kk + j] * sSv[j*25 + b];
    sTmp[e] = acc;
  }
  for (int e = t; e < kk*4; e += 64) {
    int i = e / 4, b = e % 4;
    float acc = 0.f;
    for (int j = 0; j < kk; ++j) acc += sSub[i*kk + j] * sSk[j*4 + b];
    sTk[e] = acc;
  }
  __syncthreads();
  float* Vout = Vbuf + (size_t)bw*625;
  for (int e = t; e < 625; e += 64) {
    int a = e / 25, b = e % 25;
    float acc = 0.f;
    for (int i = 0; i < kk; ++i) acc += sSv[i*25 + a] * sTmp[i*25 + b];
    if (a == b) acc += 4e-6f * (float)(1 + a);
    Vout[e] = acc;
  }
  float* Kout = Kbuf + (size_t)bw*16;
  for (int e = t; e < 16; e += 64) {
    int a = e / 4, b = e % 4;
    float acc = 0.f;
    for (int i = 0; i < kk; ++i) acc += sSk[i*4 + a] * sTk[i*4 + b];
    if (a == b) acc += 2.5e-5f * (float)(1 + a);
    Kout[e] = acc;
  }
  if (win == 29) {
    __syncthreads();
    for (int e = t; e < 100; e += 64) {
      int i = e / 4, b = e % 4;
      float acc = 0.f;
      for (int j = 0; j < 25; ++j) acc += sSub[i*25 + j] * sq3[j*4 + b];
      sTk[e] = acc;
    }
    __syncthreads();
    float* Qout = Qbuf + (size_t)bt*16;
    for (int e = t; e < 16; e += 64) {
      int a = e / 4, b = e % 4;
      float acc = 0.f;
      for (int i = 0; i < 25; ++i) acc += sq3[i*4 + a] * sTk[i*4 + b];
      if (a == b) acc += 2.5e-5f * (float)(1 + a);
      Qout[e] = acc;
    }
  }
}

// -------- batched eigh: ODD-EVEN one-sided Jacobi, rotate-and-swap --------
// Lane rl of each 16-lane row owns positions 2rl (reg a) and 2rl+1 (reg b).
// A-round: pair (2l,2l+1) = (a,b) — fully lane-local, zero cross-lane ops.
// B-round: pair (2l+1,2l+2) = (b_l, a_{l+1}) — 1 dpp_next fetch + 1 dpp_prev
// ship-back per element. Each rotation SWAPS the pair's columns, so columns
// migrate and all n(n-1)/2 pairs meet every NPOS rounds (odd-even
// transposition ordering; verified n=4 by hand: all 6 pairs in 4 rounds;
// 13*13 + 13*12 = 325 = C(26,2)). Reconstruct M = sum w_k g_k g_k^T is
// order-invariant so migration needs no bookkeeping. 4 matrices/wave.
// MODE 0: f=log(max(w,1e-9)); MODE 1: f=max(exp(w),1e-4); MODE 2: f=max(w, ln 1e-4)
__device__ __forceinline__ float dpp_prev(float v) {  // lane i <- lane i-1 (row_shr:1)
  return __int_as_float(__builtin_amdgcn_update_dpp(0, __float_as_int(v), 0x111, 0xF, 0xF, true));
}
__device__ __forceinline__ float dpp_next(float v) {  // lane i <- lane i+1 (row_shl:1)
  return __int_as_float(__builtin_amdgcn_update_dpp(0, __float_as_int(v), 0x101, 0xF, 0xF, true));
}

template<int NDATA, int MODE, int SHIFT>
__global__ __launch_bounds__(64) void eighoe_kernel(float* __restrict__ mats, float* __restrict__ norms_out)
{
  constexpr int ND   = NDATA;
  constexpr int NPOS = (ND + 1) & ~1;    // 26 / 18
  constexpr int NH   = NPOS/2;           // 13 / 9
  constexpr int NT   = ND*(ND+1)/2;
  constexpr int STG  = 4*ND*ND;
  constexpr int GNS  = 4*NPOS*ND;
  constexpr int LSZ  = (STG > GNS ? STG : GNS);

  __shared__ float lds[LSZ];
  __shared__ float wv[4*NPOS];

  int t = threadIdx.x;
  int rl = t & 15, mat = t >> 4;
  bool act   = rl < NH;
  bool isL   = rl == NH-1;
  bool actB  = act && !isL;              // B-round rotating lanes
  bool recvA = (rl >= 1) && (rl < NH);   // B-round a-receivers
  float* M = mats + (size_t)blockIdx.x*4*ND*ND;

  // stage 4 matrices (coalesced)
  for (int e = t; e < STG; e += 64) lds[e] = M[e];
  __syncthreads();

  const float* st = lds + mat*ND*ND;
  int cA = 2*rl, cB = 2*rl + 1;
  float a[ND], b[ND], ta[ND];
  float na = 0.f, nb = 0.f;
  #pragma unroll
  for (int i = 0; i < ND; ++i) {
    float va = 0.f, vb = 0.f;
    if (act) {
      va = 0.5f*(st[i*ND + cA] + st[cA*ND + i]);
      if (i == cA) va += (float)SHIFT;
      if (cB < ND) {
        vb = 0.5f*(st[i*ND + cB] + st[cB*ND + i]);
        if (i == cB) vb += (float)SHIFT;
      }
    }
    a[i] = va; b[i] = vb;
    na = fmaf(va, va, na); nb = fmaf(vb, vb, nb);
  }

  const float TOL2 = 4e-8f;              // (2e-4)^2 relative
  for (int sw = 0; sw < 9; ++sw) {
    int bad = 0;
    #pragma unroll 1
    for (int rr = 0; rr < NH; ++rr) {
      // ===== A round: local pair (a,b), rotate + swap, no cross-lane =====
      {
        float d0=0.f,d1=0.f,d2=0.f,d3=0.f,d4=0.f;
        #pragma unroll
        for (int i = 0; i < ND; ++i) {
          if      (i % 5 == 0) d0 = fmaf(a[i], b[i], d0);
          else if (i % 5 == 1) d1 = fmaf(a[i], b[i], d1);
          else if (i % 5 == 2) d2 = fmaf(a[i], b[i], d2);
          else if (i % 5 == 3) d3 = fmaf(a[i], b[i], d3);
          else                 d4 = fmaf(a[i], b[i], d4);
        }
        float d = ((d0 + d1) + (d2 + d3)) + d4;
        float ad = fabsf(d);
        float dd = (ad > 1e-36f) ? d : 1e-36f;
        float tau = (nb - na) * 0.5f * __builtin_amdgcn_rcpf(dd);
        float mag = __builtin_amdgcn_rcpf(fabsf(tau) + sqrtf(fmaf(tau, tau, 1.f)));
        float tt = copysignf(mag, tau);
        float c = __builtin_amdgcn_rsqf(fmaf(tt, tt, 1.f));
        float s = tt * c;
        #pragma unroll
        for (int i = 0; i < ND; ++i) {
          float av = a[i], bv = b[i];
          a[i] = fmaf(s, av,  c*bv);     // q' -> position 2l
          b[i] = fmaf(c, av, -(s*bv));   // p' -> position 2l+1 (swapped)
        }
        bad |= (act && (d*d > TOL2*na*nb)) ? 1 : 0;
        float csd = 2.f*c*s*d;
        float c2 = c*c, s2 = s*s;
        float nA = s2*na + c2*nb + csd;  // norm(q')
        float nB = c2*na + s2*nb - csd;  // norm(p')
        na = nA; nb = nB;
      }
      // ===== B round: pair (b_l, a_{l+1}), fetch + ship-back =====
      {
        #pragma unroll
        for (int i = 0; i < ND; ++i) ta[i] = dpp_next(a[i]);
        float n_ta = dpp_next(na);
        float d0=0.f,d1=0.f,d2=0.f,d3=0.f,d4=0.f;
        #pragma unroll
        for (int i = 0; i < ND; ++i) {
          if      (i % 5 == 0) d0 = fmaf(b[i], ta[i], d0);
          else if (i % 5 == 1) d1 = fmaf(b[i], ta[i], d1);
          else if (i % 5 == 2) d2 = fmaf(b[i], ta[i], d2);
          else if (i % 5 == 3) d3 = fmaf(b[i], ta[i], d3);
          else                 d4 = fmaf(b[i], ta[i], d4);
        }
        float d = ((d0 + d1) + (d2 + d3)) + d4;
        float ad = fabsf(d);
        float dd = (ad > 1e-36f) ? d : 1e-36f;
        float tau = (n_ta - nb) * 0.5f * __builtin_amdgcn_rcpf(dd);
        float mag = __builtin_amdgcn_rcpf(fabsf(tau) + sqrtf(fmaf(tau, tau, 1.f)));
        float tt = copysignf(mag, tau);
        float c = __builtin_amdgcn_rsqf(fmaf(tt, tt, 1.f));
        float s = tt * c;
        #pragma unroll
        for (int i = 0; i < ND; ++i) {
          float bv = b[i], tv = ta[i];
          float qv = fmaf(s, bv,  c*tv);   // q' -> stays at position 2l+1
          float pv = fmaf(c, bv, -(s*tv)); // p' -> ships to position 2l+2
          float sh = dpp_prev(pv);
          b[i] = actB  ? qv : b[i];
          a[i] = recvA ? sh : a[i];
        }
        bad |= (actB && (d*d > TOL2*nb*n_ta)) ? 1 : 0;
        float csd = 2.f*c*s*d;
        float c2 = c*c, s2 = s*s;
        float nq  = s2*nb + c2*n_ta + csd;
        float npv = c2*nb + s2*n_ta - csd;
        float shn = dpp_prev(npv);
        nb = actB  ? nq  : nb;
        na = recvA ? shn : na;
      }
    }
    // exact norm refresh (kills incremental drift)
    {
      float n0=0.f,n1=0.f,n2=0.f,n3=0.f,n4=0.f;
      float m0=0.f,m1=0.f,m2=0.f,m3=0.f,m4=0.f;
      #pragma unroll
      for (int i = 0; i < ND; ++i) {
        if      (i % 5 == 0) { n0 = fmaf(a[i],a[i],n0); m0 = fmaf(b[i],b[i],m0); }
        else if (i % 5 == 1) { n1 = fmaf(a[i],a[i],n1); m1 = fmaf(b[i],b[i],m1); }
        else if (i % 5 == 2) { n2 = fmaf(a[i],a[i],n2); m2 = fmaf(b[i],b[i],m2); }
        else if (i % 5 == 3) { n3 = fmaf(a[i],a[i],n3); m3 = fmaf(b[i],b[i],m3); }
        else                 { n4 = fmaf(a[i],a[i],n4); m4 = fmaf(b[i],b[i],m4); }
      }
      na = ((n0 + n1) + (n2 + n3)) + n4;
      nb = ((m0 + m1) + (m2 + m3)) + m4;
    }
    if (sw >= 1 && !__any(bad)) break;
  }

  // weights w = f(||g|| - SHIFT) / ||g||^2
  float lamA = sqrtf(na) - (float)SHIFT;
  float lamB = sqrtf(nb) - (float)SHIFT;
  float fA, fB;
  if (MODE == 0)      { fA = logf(fmaxf(lamA, 1e-9f));  fB = logf(fmaxf(lamB, 1e-9f)); }
  else if (MODE == 1) { fA = fmaxf(expf(lamA), 1e-4f);  fB = fmaxf(expf(lamB), 1e-4f); }
  else                { fA = fmaxf(lamA, -9.210340371976182f); fB = fmaxf(lamB, -9.210340371976182f); }
  float wA = (na < 1e-30f) ? 0.f : fA * __builtin_amdgcn_rcpf(na);
  float wB = (nb < 1e-30f) ? 0.f : fB * __builtin_amdgcn_rcpf(nb);

  __syncthreads();
  // dump columns to LDS [slot][row] (slot order irrelevant)
  float* gn = lds + mat*NPOS*ND;
  if (act) {
    #pragma unroll
    for (int i = 0; i < ND; ++i) {
      gn[rl*ND + i] = a[i];
      gn[(rl + NH)*ND + i] = b[i];
    }
    wv[mat*NPOS + rl] = wA;
    wv[mat*NPOS + rl + NH] = wB;
  }
  __syncthreads();

  // preload weights into registers (broadcast reads per row)
  float wreg[NPOS];
  #pragma unroll
  for (int k = 0; k < NPOS; ++k) wreg[k] = wv[mat*NPOS + k];

  // M = sum_k w_k g_k g_k^T (triangle, mirrored), 16 lanes per matrix
  float* Mo = M + mat*ND*ND;
  const float* g = lds + mat*NPOS*ND;
  float nacc = 0.f;
  for (int e = rl; e < NT; e += 16) {
    int i = 0, rem = e;
    while (rem >= ND - i) { rem -= ND - i; ++i; }
    int j = i + rem;
    float acc = 0.f;
    #pragma unroll
    for (int k = 0; k < NPOS; ++k) {
      float wg = wreg[k] * g[k*ND + i];
      acc = fmaf(wg, g[k*ND + j], acc);
    }
    Mo[i*ND + j] = acc;
    Mo[j*ND + i] = acc;
    nacc += (i == j) ? acc*acc : 2.f*acc*acc;
  }
  if (norms_out != nullptr) {
    nacc += __shfl_xor(nacc, 8);
    nacc += __shfl_xor(nacc, 4);
    nacc += __shfl_xor(nacc, 2);
    nacc += __shfl_xor(nacc, 1);
    if (rl == 0) norms_out[blockIdx.x*4 + mat] = nacc;
  }
}

// ---------------- per-thread 4x4 eigh -> log + Frobenius^2 ----------------
template<int P, int Q>
__device__ __forceinline__ void rot4(float a[4][4], float u[4][4])
{
  float apq = a[P][Q];
  if (fabsf(apq) < 1e-36f) return;
  float app = a[P][P], aqq = a[Q][Q];
  float tau = (aqq - app) / (2.f*apq);
  float tt = 1.f / (fabsf(tau) + sqrtf(tau*tau + 1.f));
  if (tau < 0.f) tt = -tt;
  float c = 1.f / sqrtf(tt*tt + 1.f), s = tt*c;
  #pragma unroll
  for (int k = 0; k < 4; ++k) { float akp = a[k][P], akq = a[k][Q]; a[k][P] = c*akp - s*akq; a[k][Q] = s*akp + c*akq; }
  #pragma unroll
  for (int k = 0; k < 4; ++k) { float apk = a[P][k], aqk = a[Q][k]; a[P][k] = c*apk - s*aqk; a[Q][k] = s*apk + c*aqk; }
  #pragma unroll
  for (int k = 0; k < 4; ++k) { float ukp = u[k][P], ukq = u[k][Q]; u[k][P] = c*ukp - s*ukq; u[k][Q] = s*ukp + c*ukq; }
}

__global__ __launch_bounds__(256) void eigh4_kernel(float* __restrict__ kmats, float* __restrict__ qmats,
                                                    float* __restrict__ norms)
{
  int idx = blockIdx.x*256 + threadIdx.x;
  if (idx >= 23808) return;
  float* M = (idx < 23040) ? (kmats + (size_t)idx*16) : (qmats + (size_t)(idx - 23040)*16);
  float a[4][4], u[4][4];
  #pragma unroll
  for (int i = 0; i < 4; ++i)
    #pragma unroll
    for (int j = 0; j < 4; ++j) { a[i][j] = 0.5f*(M[i*4+j] + M[j*4+i]); u[i][j] = (i == j) ? 1.f : 0.f; }
  #pragma unroll 1
  for (int sw = 0; sw < 8; ++sw) {
    rot4<0,1>(a,u); rot4<0,2>(a,u); rot4<0,3>(a,u);
    rot4<1,2>(a,u); rot4<1,3>(a,u); rot4<2,3>(a,u);
  }
  float f[4];
  #pragma unroll
  for (int i = 0; i < 4; ++i) f[i] = logf(fmaxf(a[i][i], 1e-9f));
  float nrm = 0.f;
  #pragma unroll
  for (int i = 0; i < 4; ++i)
    #pragma unroll
    for (int j = 0; j < 4; ++j) {
      float acc = 0.f;
      #pragma unroll
      for (int k = 0; k < 4; ++k) acc += u[i][k]*f[k]*u[j][k];
      M[i*4+j] = acc; nrm += acc*acc;
    }
  norms[idx] = nrm;
}

// ---------------- attention 1 (only output row 29) ----------------
__global__ __launch_bounds__(64) void att1_kernel(
    const float* __restrict__ logK, const float* __restrict__ logQ,
    const float* __restrict__ kn, const float* __restrict__ qn,
    const float* __restrict__ logV, float* __restrict__ outlog1)
{
  __shared__ float lq[16];
  __shared__ float sscore[30];
  __shared__ float sp[30];
  int bt = blockIdx.x, t = threadIdx.x;
  if (t < 16) lq[t] = logQ[(size_t)bt*16 + t];
  __syncthreads();
  if (t < 30) {
    const float* lk = logK + ((size_t)bt*30 + t)*16;
    float cr = 0.f;
    #pragma unroll
    for (int e = 0; e < 16; ++e) cr += lk[e]*lq[e];
    float E = fmaxf(kn[bt*30 + t] + qn[bt] - 2.f*cr, 0.f);
    sscore[t] = 1.f/(1.f + log1pf(E));
  }
  __syncthreads();
  float mx = -1e30f;
  for (int i = 0; i < 30; ++i) mx = fmaxf(mx, sscore[i]);
  float sm = 0.f;
  for (int i = 0; i < 30; ++i) sm += expf(sscore[i] - mx);
  if (t < 30) sp[t] = expf(sscore[t] - mx)/sm;
  __syncthreads();
  const float* lv = logV + (size_t)bt*30*625;
  float* outp = outlog1 + (size_t)bt*625;
  for (int e = t; e < 625; e += 64) {
    float acc = 0.f;
    for (int i = 0; i < 30; ++i) acc += sp[i]*lv[(size_t)i*625 + e];
    outp[e] = acc;
  }
}

// ---------------- Q2/K2/V2 = W^T xm W ----------------
__global__ __launch_bounds__(64) void qkv2_kernel(
    const float* __restrict__ xm, const float* __restrict__ mq, const float* __restrict__ mk,
    const float* __restrict__ mv, float* __restrict__ q2, float* __restrict__ k2, float* __restrict__ v2)
{
  __shared__ float sx[625], sw[450], stmp[450];
  int bt = blockIdx.x, t = threadIdx.x;
  for (int e = t; e < 625; e += 64) sx[e] = xm[(size_t)bt*625 + e];
  for (int wi = 0; wi < 3; ++wi) {
    const float* W = (wi == 0) ? mq : (wi == 1) ? mk : mv;
    float* O = ((wi == 0) ? q2 : (wi == 1) ? k2 : v2) + (size_t)bt*324;
    for (int e = t; e < 450; e += 64) sw[e] = W[e];
    __syncthreads();
    for (int e = t; e < 450; e += 64) {
      int i = e / 18, b = e % 18;
      float acc = 0.f;
      for (int j = 0; j < 25; ++j) acc += sx[i*25 + j]*sw[j*18 + b];
      stmp[e] = acc;
    }
    __syncthreads();
    for (int e = t; e < 324; e += 64) {
      int a = e / 18, b = e % 18;
      float acc = 0.f;
      for (int i = 0; i < 25; ++i) acc += sw[i*18 + a]*stmp[i*18 + b];
      O[e] = acc;
    }
    __syncthreads();
  }
}

// ---------------- attention 2 ----------------
__global__ __launch_bounds__(64) void att2_kernel(
    const float* __restrict__ logQ2, const float* __restrict__ logK2, const float* __restrict__ logV2,
    const float* __restrict__ norms, float* __restrict__ outlog2)
{
  __shared__ float S[3][3];
  __shared__ float PT[3][3];
  int b = blockIdx.x, t = threadIdx.x;
  if (t < 9) {
    int i = t / 3, j = t % 3;
    const float* lk = logK2 + ((size_t)b*3 + i)*324;
    const float* lq = logQ2 + ((size_t)b*3 + j)*324;
    float cr = 0.f;
    for (int e = 0; e < 324; ++e) cr += lk[e]*lq[e];
    float E = fmaxf(norms[768 + b*3 + i] + norms[b*3 + j] - 2.f*cr, 0.f);
    S[i][j] = 1.f/(1.f + log1pf(E));
  }
  __syncthreads();
  if (t < 3) {
    float m = fmaxf(S[0][t], fmaxf(S[1][t], S[2][t]));
    float e0 = expf(S[0][t]-m), e1 = expf(S[1][t]-m), e2 = expf(S[2][t]-m);
    float ssum = e0 + e1 + e2;
    PT[t][0] = e0/ssum; PT[t][1] = e1/ssum; PT[t][2] = e2/ssum;
  }
  __syncthreads();
  for (int e = t; e < 324; e += 64) {
    float l0 = logV2[((size_t)b*3 + 0)*324 + e];
    float l1 = logV2[((size_t)b*3 + 1)*324 + e];
    float l2 = logV2[((size_t)b*3 + 2)*324 + e];
    #pragma unroll
    for (int j = 0; j < 3; ++j)
      outlog2[((size_t)b*3 + j)*324 + e] = PT[j][0]*l0 + PT[j][1]*l1 + PT[j][2]*l2;
  }
}

// ---------------- features + linear ----------------
__global__ __launch_bounds__(64) void feat_kernel(
    const float* __restrict__ Lg, const float* __restrict__ lw, const float* __restrict__ lb,
    float* __restrict__ outp)
{
  __shared__ int tri_i[171], tri_j[171];
  int b = blockIdx.x, t = threadIdx.x;
  if (t == 0) { int f = 0; for (int i = 0; i < 18; ++i) for (int j = i; j < 18; ++j) { tri_i[f] = i; tri_j[f] = j; ++f; } }
  __syncthreads();
  float a0 = 0.f, a1 = 0.f, a2 = 0.f, a3 = 0.f;
  const float SQ2 = 1.41421356237309515f;
  for (int f = t; f < 513; f += 64) {
    int tt = f / 171, r = f % 171;
    int i = tri_i[r], j = tri_j[r];
    float coef = (i == j) ? 1.f : SQ2;
    float v = Lg[((size_t)b*3 + tt)*324 + i*18 + j] * coef;
    a0 += v*lw[0*513 + f]; a1 += v*lw[1*513 + f]; a2 += v*lw[2*513 + f]; a3 += v*lw[3*513 + f];
  }
  #pragma unroll
  for (int off = 32; off > 0; off >>= 1) {
    a0 += __shfl_down(a0, off); a1 += __shfl_down(a1, off);
    a2 += __shfl_down(a2, off); a3 += __shfl_down(a3, off);
  }
  if (t == 0) {
    outp[b*4 + 0] = a0 + lb[0]; outp[b*4 + 1] = a1 + lb[1];
    outp[b*4 + 2] = a2 + lb[2]; outp[b*4 + 3] = a3 + lb[3];
  }
}

// ---------------------------------------------------------------------------
extern "C" void kernel_launch(void* const* d_in, const int* in_sizes, int n_in,
                              void* d_out, int out_size, void* d_ws, size_t ws_size,
                              hipStream_t stream)
{
  const float* x    = (const float*)d_in[0];
  const float* c1w  = (const float*)d_in[1];
  const float* c1b  = (const float*)d_in[2];
  const float* bn1g = (const float*)d_in[3];
  const float* bn1b = (const float*)d_in[4];
  const float* bn1m = (const float*)d_in[5];
  const float* bn1v = (const float*)d_in[6];
  const float* c2w  = (const float*)d_in[7];
  const float* c2b  = (const float*)d_in[8];
  const float* bn2g = (const float*)d_in[9];
  const float* bn2b = (const float*)d_in[10];
  const float* bn2m = (const float*)d_in[11];
  const float* bn2v = (const float*)d_in[12];
  const float* sk0  = (const float*)d_in[14];
  const float* sv0  = (const float*)d_in[15];
  const float* sk1  = (const float*)d_in[17];
  const float* sv1  = (const float*)d_in[18];
  const float* sk2  = (const float*)d_in[20];
  const float* sv2  = (const float*)d_in[21];
  const float* sq3  = (const float*)d_in[22];
  const float* sk3  = (const float*)d_in[23];
  const float* sv3  = (const float*)d_in[24];
  const float* mq   = (const float*)d_in[25];
  const float* mk   = (const float*)d_in[26];
  const float* mv   = (const float*)d_in[27];
  const float* lw   = (const float*)d_in[28];
  const float* lb   = (const float*)d_in[29];
  float* outp = (float*)d_out;

  float* ws = (float*)d_ws;
  float* covs = ws;                       // 480000
  float* ybn1 = ws + 480000;              // 5632000
  float* sig  = ws + 6112000;             // 6406400
  float* Vbuf = ws + 480000;              // 14400000 (reuses dead ybn1/sig)
  float* Kbuf = ws + 14880000;            // 368640
  float* Qbuf = ws + 15248640;            // 12288
  float* knb  = ws + 15260928;            // 23808
  float* ol1  = ws + 15284736;            // 480000
  float* qkv2 = ws + 15764736;            // 746496
  float* nrm2 = ws + 16511232;            // 2304
  float* ol2  = ws + 16513536;            // 248832

  conv1_kernel<<<1000, 256, 0, stream>>>(x, c1w, c1b, bn1g, bn1b, bn1m, bn1v, ybn1);
  conv2_kernel<<<1001, 256, 0, stream>>>(ybn1, c2w, c2b, bn2g, bn2b, bn2m, bn2v, sig);
  spd_kernel<<<768, 256, 0, stream>>>(sig, covs);
  build_windows_kernel<<<23040, 64, 0, stream>>>(covs, sk0, sk1, sk2, sk3, sv0, sv1, sv2, sv3, sq3,
                                                 Vbuf, Kbuf, Qbuf);
  eighoe_kernel<25,0,0><<<5760, 64, 0, stream>>>(Vbuf, nullptr);           // logV in place
  eigh4_kernel<<<93, 256, 0, stream>>>(Kbuf, Qbuf, knb);                   // logK/logQ + norms
  att1_kernel<<<768, 64, 0, stream>>>(Kbuf, Qbuf, knb, knb + 23040, Vbuf, ol1);
  eighoe_kernel<25,1,16><<<192, 64, 0, stream>>>(ol1, nullptr);            // xm = rect(exp(.)), shifted
  qkv2_kernel<<<768, 64, 0, stream>>>(ol1, mq, mk, mv, qkv2, qkv2 + 248832, qkv2 + 497664);
  eighoe_kernel<18,0,0><<<576, 64, 0, stream>>>(qkv2, nrm2);               // logs + norms
  att2_kernel<<<256, 64, 0, stream>>>(qkv2, qkv2 + 248832, qkv2 + 497664, nrm2, ol2);
  eighoe_kernel<18,2,16><<<192, 64, 0, stream>>>(ol2, nullptr);            // Lg, shifted
  feat_kernel<<<256, 64, 0, stream>>>(ol2, lw, lb, outp);
}